// Round 4
// baseline (344.083 us; speedup 1.0000x reference)
//
#include <hip/hip_runtime.h>
#include <hip/hip_bf16.h>
#include <math.h>

// ---------------------------------------------------------------------------
// GuoCapSAREncoder round 17: conv2 icc-SPLIT. r13-r16 A/B showed conv2 is
// latency-bound on its A-load/ds_read->MFMA chain with grid=512 (2 blocks/CU)
// the binding constraint (LDS 51.7KB already admits 3/CU). The two icc
// K-halves are independent accumulations -> gridDim.z=2 (1024 blocks), each
// block = exact r13 per-wave structure (192thr, nt=2, 4 MFMA / 2 A-loads,
// same LDS slab for its own 64 channels, half the iterations). Blocks write
// fp32 PARTIALS (numerically == old fp32 accumulation, reordered add);
// convcaps staging folds p0+p1+bias -> bf16 -> LDS (it re-staged h2 anyway).
// Zero added MFMA, zero added h1n fetch, no numerics risk.
// All other kernels frozen from round 16.
// ---------------------------------------------------------------------------

#define EPSF 1e-8f

typedef __bf16 bf16x8 __attribute__((ext_vector_type(8)));
typedef __bf16 bf16x4 __attribute__((ext_vector_type(4)));
typedef float floatx4 __attribute__((ext_vector_type(4)));
typedef float floatx16 __attribute__((ext_vector_type(16)));

// ---- weight transposes ----------------------------------------------------
__global__ __launch_bounds__(256) void k_t_w1b(const float* __restrict__ w1, __bf16* __restrict__ w1b) {
    int i = blockIdx.x * 256 + threadIdx.x;          // 12*128*8 = 12288
    if (i >= 12288) return;
    int kt = i >> 10, oc = (i >> 3) & 127, j = i & 7;
    int k = kt * 8 + j;
    w1b[i] = (__bf16)(k < 81 ? w1[oc * 81 + k] : 0.f);
}

// w2[oc64][ic128][khw25] -> w2a frag-ready: f = ((icc*25+khw)*4+ks)*2+mt,
// element [f][lane=h*32+c32][j] = w2[mt*32+c32][icc*64+ks*16+h*8+j][khw]
__global__ __launch_bounds__(256) void k_t_w2a(const float* __restrict__ w2, __bf16* __restrict__ w2a) {
    int i = blockIdx.x * 256 + threadIdx.x;          // 204800
    if (i >= 204800) return;
    int j = i & 7, lane = (i >> 3) & 63, f = i >> 9;
    int mt = f & 1, ks = (f >> 1) & 3, rem = f >> 3;
    int khw = rem % 25, icc = rem / 25;
    int c32 = lane & 31, h = lane >> 5;
    int oc = mt * 32 + c32;
    int ic = icc * 64 + ks * 16 + h * 8 + j;
    w2a[i] = (__bf16)w2[(oc * 128 + ic) * 25 + khw];
}

// wc[oc128][ic64][khw64] -> wca frag-ready: f = (((icc*64+khw)*2+ks)*4+ct,
// element [f][lane][j] = wc[ct*32+c32][icc*32+ks*16+h*8+j][khw]
__global__ __launch_bounds__(256) void k_t_wca(const float* __restrict__ wc, __bf16* __restrict__ wca) {
    int i = blockIdx.x * 256 + threadIdx.x;          // 524288
    if (i >= 524288) return;
    int j = i & 7, lane = (i >> 3) & 63, f = i >> 9;
    int ct = f & 3, ks = (f >> 2) & 1, khw = (f >> 3) & 63, icc = f >> 9;
    int c32 = lane & 31, h = lane >> 5;
    int oc = ct * 32 + c32;
    int ic = icc * 32 + ks * 16 + h * 8 + j;
    wca[i] = (__bf16)wc[(oc * 64 + ic) * 64 + khw];
}

__global__ __launch_bounds__(256) void k_t_wrb(const float* __restrict__ Wr, __bf16* __restrict__ wrb) {
    int i = blockIdx.x * 256 + threadIdx.x;          // 5242880
    if (i >= 5242880) return;
    wrb[i] = (__bf16)Wr[i];
}

// ---- conv1 9x9 + ReLU + maxpool2 via MFMA -> h1n NHWC bf16 [b][42][42][128]
__global__ __launch_bounds__(256, 3) void k_conv1_mfma(const float* __restrict__ x,
                                                       const __bf16* __restrict__ w1b,
                                                       const float* __restrict__ b1,
                                                       __bf16* __restrict__ h1n) {
    __shared__ float xs[960];                        // 10 rows x 92 fp32 (+pad)
    __shared__ __bf16 Bl[18432];                     // 12kt x 2row x 96pos x 8j
    int py = blockIdx.x, ocg = blockIdx.y, b = blockIdx.z;
    int t = threadIdx.x;
    int lane = t & 63, w = t >> 6;
    int cc = lane & 15, q = lane >> 4;

    const float* xb = x + (size_t)b * 8464 + 2 * py * 92;
    for (int j = t; j < 920; j += 256) xs[j] = xb[j];

    int ocA = ocg * 64 + w * 16 + cc;
    bf16x8 af[3];
#pragma unroll
    for (int ks = 0; ks < 3; ++ks)
        af[ks] = *(const bf16x8*)(w1b + ((ks * 4 + q) * 128 + ocA) * 8);

    __syncthreads();

    if (t < 192) {
        int row = t / 96, pos = t - (t / 96) * 96;
        int sbase = row * 92 + pos;
        bool pvalid = pos < 84;
#pragma unroll
        for (int kt = 0; kt < 12; ++kt) {
            bf16x8 pk;
#pragma unroll
            for (int j = 0; j < 8; ++j) {
                int k = kt * 8 + j;
                int kh = k / 9, kw = k - kh * 9;
                float v = (pvalid && k < 81) ? xs[sbase + kh * 92 + kw] : 0.f;
                pk[j] = (__bf16)v;
            }
            *(bf16x8*)(Bl + ((kt * 2 + row) * 96 + pos) * 8) = pk;
        }
    }
    __syncthreads();

    floatx4 acc[2][6];
    const char* Bb = (const char*)Bl + cc * 16 + q * 3072;
#pragma unroll
    for (int rr = 0; rr < 2; ++rr)
#pragma unroll
        for (int n6 = 0; n6 < 6; ++n6) {
            floatx4 a = (floatx4){0.f, 0.f, 0.f, 0.f};
#pragma unroll
            for (int ks = 0; ks < 3; ++ks) {
                bf16x8 bf = *(const bf16x8*)(Bb + ks * 12288 + rr * 1536 + n6 * 256);
                a = __builtin_amdgcn_mfma_f32_16x16x32_bf16(af[ks], bf, a, 0, 0, 0);
            }
            acc[rr][n6] = a;
        }

    int oc0 = ocg * 64 + w * 16 + q * 4;
    float4 bv = *(const float4*)(b1 + oc0);
    size_t obase = (((size_t)b * 42 + py) * 42) * 128 + oc0;
#pragma unroll
    for (int n6 = 0; n6 < 6; ++n6) {
        bf16x4 pk;
#pragma unroll
        for (int r = 0; r < 4; ++r) {
            float vert = fmaxf(acc[0][n6][r], acc[1][n6][r]);
            float hz = fmaxf(vert, __shfl_xor(vert, 1, 64));
            float pooled = fmaxf(hz + ((const float*)&bv)[r], 0.f);
            pk[r] = (__bf16)pooled;
        }
        if ((cc & 1) == 0) {
            int px = n6 * 8 + (cc >> 1);
            if (px < 42)
                *(bf16x4*)(h1n + obase + (size_t)px * 128) = pk;
        }
    }
}

// ---- conv2 5x5 via MFMA 32x32x16, icc-split: h1n -> fp32 partials ---------
// grid (8, 64, 2); block = r13 structure for ONE icc half; writes fp32
// partial (no bias) to p01 + icc*5914624, layout [b][38][38][64] f32.
__global__ __launch_bounds__(192, 2) void k_conv2(const __bf16* __restrict__ h1n,
                                                  const __bf16* __restrict__ w2a,
                                                  float* __restrict__ p01) {
    __shared__ __bf16 ins[25704];                    // 378 pos * 136 B = 51408 B
    int g = blockIdx.x, b = blockIdx.y, icc = blockIdx.z;
    int row0 = g * 5;
    int t = threadIdx.x;
    int lane = t & 63, w = t >> 6;                   // w in [0,3)
    int c32 = lane & 31, h = lane >> 5;
    int validp = (g < 7) ? 190 : 114;
    int ic0 = icc * 64;

    int baseN[2], posi[2];
#pragma unroll
    for (int nt = 0; nt < 2; ++nt) {
        int pi = (w * 2 + nt) * 32 + c32;
        int pc = pi < validp ? pi : validp - 1;
        int r = pc / 38, c = pc - r * 38;
        posi[nt] = pi;
        baseN[nt] = (r * 42 + c) * 136 + h * 16;
    }

    // batched staging: 16 fixed slots per thread (3024 total, tail clamped)
#pragma unroll
    for (int half = 0; half < 2; ++half) {
        uint4 rb[8];
        int lo[8];
#pragma unroll
        for (int k = 0; k < 8; ++k) {
            int j = (half * 8 + k) * 192 + t;
            if (j > 3023) j -= 192;                  // only k=7,half=1,t>=144
            int lr = j / 336, rem = j - lr * 336;
            int ix = rem >> 3, sb = rem & 7;
            int rg = row0 + lr; if (rg > 41) rg = 41;
            rb[k] = *(const uint4*)(h1n + ((((size_t)b * 42 + rg) * 42 + ix) * 128 + ic0 + sb * 8));
            lo[k] = (lr * 42 + ix) * 136 + sb * 16;
        }
#pragma unroll
        for (int k = 0; k < 8; ++k)
            *(uint4*)((char*)ins + lo[k]) = rb[k];
    }

    floatx16 acc[2][2];
#pragma unroll
    for (int mt = 0; mt < 2; ++mt)
#pragma unroll
        for (int nt = 0; nt < 2; ++nt)
#pragma unroll
            for (int i = 0; i < 16; ++i) acc[mt][nt][i] = 0.f;

    __syncthreads();
    const __bf16* wic = w2a + (size_t)icc * 25 * 4096 + (lane << 3);
#pragma unroll
    for (int khw = 0; khw < 25; ++khw) {
        int kh = khw / 5, kw = khw - kh * 5;
        int doff = (kh * 42 + kw) * 136;
        const __bf16* wk = wic + khw * 4096;         // 4 ks x 2 mt x 512
#pragma unroll
        for (int ks = 0; ks < 4; ++ks) {
            bf16x8 a0 = *(const bf16x8*)(wk + ks * 1024);
            bf16x8 a1 = *(const bf16x8*)(wk + ks * 1024 + 512);
#pragma unroll
            for (int nt = 0; nt < 2; ++nt) {
                bf16x8 bfr = *(const bf16x8*)((char*)ins + baseN[nt] + doff + ks * 32);
                acc[0][nt] = __builtin_amdgcn_mfma_f32_32x32x16_bf16(a0, bfr, acc[0][nt], 0, 0, 0);
                acc[1][nt] = __builtin_amdgcn_mfma_f32_32x32x16_bf16(a1, bfr, acc[1][nt], 0, 0, 0);
            }
        }
    }
    float* pdst = p01 + (size_t)icc * 5914624;
#pragma unroll
    for (int nt = 0; nt < 2; ++nt) {
        int pi = posi[nt];
        if (pi < validp) {
            int r = pi / 38, c = pi - r * 38;
            int oh = row0 + r;
            size_t obase = (((size_t)b * 38 + oh) * 38 + c) * 64;
#pragma unroll
            for (int mt = 0; mt < 2; ++mt) {
#pragma unroll
                for (int g2 = 0; g2 < 4; ++g2) {
                    int oc0 = mt * 32 + g2 * 8 + h * 4;
                    floatx4 pv;
                    pv[0] = acc[mt][nt][g2 * 4 + 0];
                    pv[1] = acc[mt][nt][g2 * 4 + 1];
                    pv[2] = acc[mt][nt][g2 * 4 + 2];
                    pv[3] = acc[mt][nt][g2 * 4 + 3];
                    *(floatx4*)(pdst + obase + oc0) = pv;
                }
            }
        }
    }
}

// ---- caps conv 8x8 s2 via MFMA 32x32x16 + FUSED squash -> ub bf16 ---------
// Staging reads fp32 partials p0,p1, folds p0+p1+b2 -> bf16 -> LDS.
__global__ __launch_bounds__(256, 4) void k_convcaps(const float* __restrict__ p01,
                                                     const __bf16* __restrict__ wca,
                                                     const float* __restrict__ b2,
                                                     const float* __restrict__ bc,
                                                     __bf16* __restrict__ ub) {
    __shared__ __bf16 ins[13680];                    // 380 * 72 B = 27360 B
    int g = blockIdx.x, b = blockIdx.y;              // g in [0,8)
    int t = threadIdx.x;
    int lane = t & 63, ct = t >> 6;                  // wave = capsule type
    int c32 = lane & 31, h = lane >> 5;
    int rloc = c32 >> 4, cx = c32 & 15;

    floatx16 acc;
#pragma unroll
    for (int i = 0; i < 16; ++i) acc[i] = 0.f;

    int Bbase = (76 * rloc + cx) * 72 + h * 16;      // lane byte base in slab
    for (int icc = 0; icc < 2; ++icc) {
        int ic0 = icc * 32;
        __syncthreads();
        // 6 slots/thread in 3 batches of 2: per slot read p0 lo/hi + p1 lo/hi
#pragma unroll
        for (int bt = 0; bt < 3; ++bt) {
            floatx4 rA[2], rB[2], rC[2], rD[2], bL[2], bH[2];
            int lo[2];
#pragma unroll
            for (int k = 0; k < 2; ++k) {
                int j = (bt * 2 + k) * 256 + t;
                if (j > 1519) j -= 256;              // only bt=2,k=1,t>=240
                int r = j / 152, rem = j - r * 152;
                int c = rem >> 2, s = rem & 3;
                size_t bf = ((((size_t)b * 38 + 4 * g + r) * 38 + c) * 64 + ic0 + s * 8);
                rA[k] = *(const floatx4*)(p01 + bf);
                rB[k] = *(const floatx4*)(p01 + bf + 4);
                rC[k] = *(const floatx4*)(p01 + 5914624 + bf);
                rD[k] = *(const floatx4*)(p01 + 5914624 + bf + 4);
                bL[k] = *(const floatx4*)(b2 + ic0 + s * 8);
                bH[k] = *(const floatx4*)(b2 + ic0 + s * 8 + 4);
                int X = (r * 2 + (c & 1)) * 19 + (c >> 1);
                lo[k] = X * 72 + s * 16;
            }
#pragma unroll
            for (int k = 0; k < 2; ++k) {
                bf16x8 pk;
#pragma unroll
                for (int e = 0; e < 4; ++e) {
                    pk[e]     = (__bf16)(rA[k][e] + rC[k][e] + bL[k][e]);
                    pk[4 + e] = (__bf16)(rB[k][e] + rD[k][e] + bH[k][e]);
                }
                *(bf16x8*)((char*)ins + lo[k]) = pk;
            }
        }
        __syncthreads();
        const __bf16* wic = wca + ((size_t)icc * 64 * 8 + ct) * 512 + (lane << 3);
#pragma unroll
        for (int khw = 0; khw < 64; ++khw) {
            int kh = khw >> 3, kw = khw & 7;
            int par = kw & 1, k2 = kw >> 1;
            int doff = ((kh * 2 + par) * 19 + k2) * 72;
            const __bf16* wk = wic + khw * 4096;     // 2 ks x 4 ct x 512
#pragma unroll
            for (int ks = 0; ks < 2; ++ks) {
                bf16x8 af = *(const bf16x8*)(wk + ks * 2048);
                bf16x8 bfr = *(const bf16x8*)((char*)ins + Bbase + doff + ks * 32);
                acc = __builtin_amdgcn_mfma_f32_32x32x16_bf16(af, bfr, acc, 0, 0, 0);
            }
        }
    }
    // fused bias + squash
    float vals[16];
    float n2p = 0.f;
#pragma unroll
    for (int g2 = 0; g2 < 4; ++g2) {
        float4 bv = *(const float4*)(bc + ct * 32 + g2 * 8 + h * 4);
#pragma unroll
        for (int j = 0; j < 4; ++j) {
            float v = acc[g2 * 4 + j] + ((const float*)&bv)[j];
            vals[g2 * 4 + j] = v;
            n2p = fmaf(v, v, n2p);
        }
    }
    float n2 = n2p + __shfl_xor(n2p, 32, 64);
    float scale = (n2 / (1.f + n2)) / sqrtf(n2 + EPSF);
    int pos = (2 * g + rloc) * 16 + cx;              // y*16 + x
    __bf16* dst = ub + (((size_t)b * 1024 + ct * 256 + pos) * 32);
#pragma unroll
    for (int g2 = 0; g2 < 4; ++g2) {
        bf16x4 pk;
        pk.x = (__bf16)(vals[g2 * 4 + 0] * scale);
        pk.y = (__bf16)(vals[g2 * 4 + 1] * scale);
        pk.z = (__bf16)(vals[g2 * 4 + 2] * scale);
        pk.w = (__bf16)(vals[g2 * 4 + 3] * scale);
        *(bf16x4*)(dst + g2 * 8 + h * 4) = pk;
    }
}

// ---- u_hat: ub bf16 [64,1024,32] x wrb bf16 [1024,10,16,32] -> uhT bf16 ---
__global__ __launch_bounds__(256, 2) void k_uhat(const __bf16* __restrict__ ub,
                                                 const __bf16* __restrict__ wrb,
                                                 __bf16* __restrict__ uhT) {
    int pt = blockIdx.x, ts = blockIdx.y, bz = blockIdx.z;
    int t = threadIdx.x;
    int p = pt * 64 + (t & 63);
    int q = t >> 6;
    bf16x8 wf[4][4];
#pragma unroll
    for (int o4 = 0; o4 < 4; ++o4)
#pragma unroll
        for (int j = 0; j < 4; ++j)
            wf[o4][j] = *(const bf16x8*)(wrb + (((size_t)p * 10 + ts) * 16 + q * 4 + o4) * 32 + j * 8);
#pragma unroll 1
    for (int bi = 0; bi < 16; ++bi) {
        int b = bz * 16 + bi;
        bf16x8 uf[4];
        const bf16x8* up = (const bf16x8*)(ub + ((size_t)b * 1024 + p) * 32);
#pragma unroll
        for (int j = 0; j < 4; ++j) uf[j] = up[j];
#pragma unroll
        for (int o4 = 0; o4 < 4; ++o4) {
            float s = 0.f;
#pragma unroll
            for (int j = 0; j < 4; ++j)
#pragma unroll
                for (int e = 0; e < 8; ++e)
                    s = fmaf((float)uf[j][e], (float)wf[o4][j][e], s);
            uhT[(((size_t)b * 10 + ts) * 16 + q * 4 + o4) * 1024 + p] = (__bf16)s;
        }
    }
}

// ---- routing: s = sum_p softmax(bl)_pt * u_hat ; v = squash(s) ------------
__global__ __launch_bounds__(256) void k_route_s(const __bf16* __restrict__ uhT,
                                                 const float* __restrict__ bl,
                                                 float* __restrict__ vout,
                                                 float* __restrict__ out,
                                                 int first, int last) {
    __shared__ float sred[4][16];
    int b = blockIdx.x, tt = blockIdx.y;
    int t = threadIdx.x;
    float acc[16];
#pragma unroll
    for (int o = 0; o < 16; ++o) acc[o] = 0.f;
    const float* blb = bl + b * 10240;
    const __bf16* uhb = uhT + ((size_t)b * 10 + tt) * 16384;
    for (int p = t; p < 1024; p += 256) {
        float c;
        if (first) {
            c = 0.1f;
        } else {
            float den = 0.f, et = 0.f;
#pragma unroll
            for (int tp = 0; tp < 10; ++tp) {
                float e = expf(blb[tp * 1024 + p]);
                den += e;
                if (tp == tt) et = e;
            }
            c = et / den;
        }
#pragma unroll
        for (int o = 0; o < 16; ++o)
            acc[o] = fmaf(c, (float)uhb[o * 1024 + p], acc[o]);
    }
    int lane = t & 63, wid = t >> 6;
#pragma unroll
    for (int o = 0; o < 16; ++o) {
        float v = acc[o];
#pragma unroll
        for (int off = 32; off >= 1; off >>= 1) v += __shfl_xor(v, off, 64);
        if (lane == 0) sred[wid][o] = v;
    }
    __syncthreads();
    if (t < 16) {
        float s = (sred[0][t] + sred[1][t]) + (sred[2][t] + sred[3][t]);
        float n2 = s * s;
#pragma unroll
        for (int off = 1; off < 16; off <<= 1) n2 += __shfl_xor(n2, off, 16);
        float scale = (n2 / (1.f + n2)) / sqrtf(n2 + EPSF);
        vout[(b * 10 + tt) * 16 + t] = s * scale;
        if (last && t == 0) {
            float sv2 = n2 * scale * scale;
            out[b * 10 + tt] = sqrtf(sv2 + EPSF);
        }
    }
}

// ---- routing: bl (+)= sum_o u_hat * v -------------------------------------
__global__ __launch_bounds__(256) void k_route_b(const __bf16* __restrict__ uhT,
                                                 const float* __restrict__ vv,
                                                 float* __restrict__ bl,
                                                 int first) {
    __shared__ float vs[16];
    int b = blockIdx.x, tt = blockIdx.y;
    int t = threadIdx.x;
    if (t < 16) vs[t] = vv[(b * 10 + tt) * 16 + t];
    __syncthreads();
    const __bf16* uhb = uhT + ((size_t)b * 10 + tt) * 16384;
    float* blb = bl + (b * 10 + tt) * 1024;
    for (int p = t; p < 1024; p += 256) {
        float d = 0.f;
#pragma unroll
        for (int o = 0; o < 16; ++o) d = fmaf((float)uhb[o * 1024 + p], vs[o], d);
        blb[p] = first ? d : (blb[p] + d);
    }
}

// ---------------------------------------------------------------------------
extern "C" void kernel_launch(void* const* d_in, const int* in_sizes, int n_in,
                              void* d_out, int out_size, void* d_ws, size_t ws_size,
                              hipStream_t stream) {
    const float* x  = (const float*)d_in[0];
    const float* w1 = (const float*)d_in[1];
    const float* b1 = (const float*)d_in[2];
    const float* w2 = (const float*)d_in[3];
    const float* b2 = (const float*)d_in[4];
    const float* wc = (const float*)d_in[5];
    const float* bc = (const float*)d_in[6];
    const float* Wr = (const float*)d_in[7];
    float* out = (float*)d_out;
    float* ws  = (float*)d_ws;

    // workspace layout (float offsets)
    __bf16* w2a = (__bf16*)(ws);                  // 204800 bf16
    __bf16* wca = (__bf16*)(ws + 102400);         // 524288 bf16
    __bf16* w1b = (__bf16*)(ws + 364544);         // 12288 bf16
    __bf16* h1n = (__bf16*)(ws + 375040);         // 14450688 bf16
    __bf16* ub  = (__bf16*)(ws + 12654848);       // 2097152 bf16
    float*  bl  = ws + 14752000;                  // 655360 f
    float*  vv  = ws + 15407360;                  // 10240 f
    __bf16* wrb = (__bf16*)(ws + 15417600);       // 5242880 bf16
    float*  p01 = ws + 18039040;                  // 2 x 5914624 f32 partials
    __bf16* uhT = (__bf16*)(ws + 375040);         // overlays h1n (dead by k_uhat)

    k_t_w1b<<<48, 256, 0, stream>>>(w1, w1b);
    k_t_w2a<<<800, 256, 0, stream>>>(w2, w2a);
    k_t_wca<<<2048, 256, 0, stream>>>(wc, wca);
    k_t_wrb<<<20480, 256, 0, stream>>>(Wr, wrb);
    k_conv1_mfma<<<dim3(42, 2, 64), 256, 0, stream>>>(x, w1b, b1, h1n);
    k_conv2<<<dim3(8, 64, 2), 192, 0, stream>>>(h1n, w2a, p01);
    k_convcaps<<<dim3(8, 64), 256, 0, stream>>>(p01, wca, b2, bc, ub);
    k_uhat<<<dim3(16, 10, 4), 256, 0, stream>>>(ub, wrb, uhT);
    k_route_s<<<dim3(64, 10), 256, 0, stream>>>(uhT, bl, vv, out, 1, 0);
    k_route_b<<<dim3(64, 10), 256, 0, stream>>>(uhT, vv, bl, 1);
    k_route_s<<<dim3(64, 10), 256, 0, stream>>>(uhT, bl, vv, out, 0, 0);
    k_route_b<<<dim3(64, 10), 256, 0, stream>>>(uhT, vv, bl, 0);
    k_route_s<<<dim3(64, 10), 256, 0, stream>>>(uhT, bl, vv, out, 0, 1);
}

// Round 5
// 324.168 us; speedup vs baseline: 1.0614x; 1.0614x over previous
//
#include <hip/hip_runtime.h>
#include <hip/hip_bf16.h>
#include <math.h>

// ---------------------------------------------------------------------------
// GuoCapSAREncoder round 18: conv2 split over OUTPUT CHANNELS (mt), not K.
// r17 proved the occupancy mechanism (conv2 ~87->~68 via grid doubling) but
// fp32 partials made convcaps re-fetch 54MB (+36us). mt-split: each block
// computes 32 complete output channels (full K), writes its disjoint bf16
// half of h2n directly with bias -> no partials, no reduction. Grid
// (8,64,2)=1024 blocks, 192thr, same 51.4KB LDS (3 blocks/CU now actually
// fed by the grid -> 9 waves/CU), nt=2 per-wave ILP intact. h1n re-stage
// x2 is L3-absorbed (29MB). convcaps reverted to r16 (bf16 h2n, ~45us).
// ---------------------------------------------------------------------------

#define EPSF 1e-8f

typedef __bf16 bf16x8 __attribute__((ext_vector_type(8)));
typedef __bf16 bf16x4 __attribute__((ext_vector_type(4)));
typedef float floatx4 __attribute__((ext_vector_type(4)));
typedef float floatx16 __attribute__((ext_vector_type(16)));

// ---- weight transposes ----------------------------------------------------
__global__ __launch_bounds__(256) void k_t_w1b(const float* __restrict__ w1, __bf16* __restrict__ w1b) {
    int i = blockIdx.x * 256 + threadIdx.x;          // 12*128*8 = 12288
    if (i >= 12288) return;
    int kt = i >> 10, oc = (i >> 3) & 127, j = i & 7;
    int k = kt * 8 + j;
    w1b[i] = (__bf16)(k < 81 ? w1[oc * 81 + k] : 0.f);
}

// w2[oc64][ic128][khw25] -> w2a frag-ready: f = ((icc*25+khw)*4+ks)*2+mt,
// element [f][lane=h*32+c32][j] = w2[mt*32+c32][icc*64+ks*16+h*8+j][khw]
__global__ __launch_bounds__(256) void k_t_w2a(const float* __restrict__ w2, __bf16* __restrict__ w2a) {
    int i = blockIdx.x * 256 + threadIdx.x;          // 204800
    if (i >= 204800) return;
    int j = i & 7, lane = (i >> 3) & 63, f = i >> 9;
    int mt = f & 1, ks = (f >> 1) & 3, rem = f >> 3;
    int khw = rem % 25, icc = rem / 25;
    int c32 = lane & 31, h = lane >> 5;
    int oc = mt * 32 + c32;
    int ic = icc * 64 + ks * 16 + h * 8 + j;
    w2a[i] = (__bf16)w2[(oc * 128 + ic) * 25 + khw];
}

// wc[oc128][ic64][khw64] -> wca frag-ready: f = (((icc*64+khw)*2+ks)*4+ct,
// element [f][lane][j] = wc[ct*32+c32][icc*32+ks*16+h*8+j][khw]
__global__ __launch_bounds__(256) void k_t_wca(const float* __restrict__ wc, __bf16* __restrict__ wca) {
    int i = blockIdx.x * 256 + threadIdx.x;          // 524288
    if (i >= 524288) return;
    int j = i & 7, lane = (i >> 3) & 63, f = i >> 9;
    int ct = f & 3, ks = (f >> 2) & 1, khw = (f >> 3) & 63, icc = f >> 9;
    int c32 = lane & 31, h = lane >> 5;
    int oc = ct * 32 + c32;
    int ic = icc * 32 + ks * 16 + h * 8 + j;
    wca[i] = (__bf16)wc[(oc * 64 + ic) * 64 + khw];
}

__global__ __launch_bounds__(256) void k_t_wrb(const float* __restrict__ Wr, __bf16* __restrict__ wrb) {
    int i = blockIdx.x * 256 + threadIdx.x;          // 5242880
    if (i >= 5242880) return;
    wrb[i] = (__bf16)Wr[i];
}

// ---- conv1 9x9 + ReLU + maxpool2 via MFMA -> h1n NHWC bf16 [b][42][42][128]
__global__ __launch_bounds__(256, 3) void k_conv1_mfma(const float* __restrict__ x,
                                                       const __bf16* __restrict__ w1b,
                                                       const float* __restrict__ b1,
                                                       __bf16* __restrict__ h1n) {
    __shared__ float xs[960];                        // 10 rows x 92 fp32 (+pad)
    __shared__ __bf16 Bl[18432];                     // 12kt x 2row x 96pos x 8j
    int py = blockIdx.x, ocg = blockIdx.y, b = blockIdx.z;
    int t = threadIdx.x;
    int lane = t & 63, w = t >> 6;
    int cc = lane & 15, q = lane >> 4;

    const float* xb = x + (size_t)b * 8464 + 2 * py * 92;
    for (int j = t; j < 920; j += 256) xs[j] = xb[j];

    int ocA = ocg * 64 + w * 16 + cc;
    bf16x8 af[3];
#pragma unroll
    for (int ks = 0; ks < 3; ++ks)
        af[ks] = *(const bf16x8*)(w1b + ((ks * 4 + q) * 128 + ocA) * 8);

    __syncthreads();

    if (t < 192) {
        int row = t / 96, pos = t - (t / 96) * 96;
        int sbase = row * 92 + pos;
        bool pvalid = pos < 84;
#pragma unroll
        for (int kt = 0; kt < 12; ++kt) {
            bf16x8 pk;
#pragma unroll
            for (int j = 0; j < 8; ++j) {
                int k = kt * 8 + j;
                int kh = k / 9, kw = k - kh * 9;
                float v = (pvalid && k < 81) ? xs[sbase + kh * 92 + kw] : 0.f;
                pk[j] = (__bf16)v;
            }
            *(bf16x8*)(Bl + ((kt * 2 + row) * 96 + pos) * 8) = pk;
        }
    }
    __syncthreads();

    floatx4 acc[2][6];
    const char* Bb = (const char*)Bl + cc * 16 + q * 3072;
#pragma unroll
    for (int rr = 0; rr < 2; ++rr)
#pragma unroll
        for (int n6 = 0; n6 < 6; ++n6) {
            floatx4 a = (floatx4){0.f, 0.f, 0.f, 0.f};
#pragma unroll
            for (int ks = 0; ks < 3; ++ks) {
                bf16x8 bf = *(const bf16x8*)(Bb + ks * 12288 + rr * 1536 + n6 * 256);
                a = __builtin_amdgcn_mfma_f32_16x16x32_bf16(af[ks], bf, a, 0, 0, 0);
            }
            acc[rr][n6] = a;
        }

    int oc0 = ocg * 64 + w * 16 + q * 4;
    float4 bv = *(const float4*)(b1 + oc0);
    size_t obase = (((size_t)b * 42 + py) * 42) * 128 + oc0;
#pragma unroll
    for (int n6 = 0; n6 < 6; ++n6) {
        bf16x4 pk;
#pragma unroll
        for (int r = 0; r < 4; ++r) {
            float vert = fmaxf(acc[0][n6][r], acc[1][n6][r]);
            float hz = fmaxf(vert, __shfl_xor(vert, 1, 64));
            float pooled = fmaxf(hz + ((const float*)&bv)[r], 0.f);
            pk[r] = (__bf16)pooled;
        }
        if ((cc & 1) == 0) {
            int px = n6 * 8 + (cc >> 1);
            if (px < 42)
                *(bf16x4*)(h1n + obase + (size_t)px * 128) = pk;
        }
    }
}

// ---- conv2 5x5 via MFMA 32x32x16, mt-split: h1n -> h2n bf16 ---------------
// grid (8, 64, 2); block computes 32 output channels (mt = blockIdx.z) with
// full K (both icc). r13 per-wave structure, nt=2, batched staging.
__global__ __launch_bounds__(192, 2) void k_conv2(const __bf16* __restrict__ h1n,
                                                  const __bf16* __restrict__ w2a,
                                                  const float* __restrict__ b2,
                                                  __bf16* __restrict__ h2n) {
    __shared__ __bf16 ins[25704];                    // 378 pos * 136 B = 51408 B
    int g = blockIdx.x, b = blockIdx.y, mt = blockIdx.z;
    int row0 = g * 5;
    int t = threadIdx.x;
    int lane = t & 63, w = t >> 6;                   // w in [0,3)
    int c32 = lane & 31, h = lane >> 5;
    int validp = (g < 7) ? 190 : 114;

    int baseN[2], posi[2];
#pragma unroll
    for (int nt = 0; nt < 2; ++nt) {
        int pi = (w * 2 + nt) * 32 + c32;
        int pc = pi < validp ? pi : validp - 1;
        int r = pc / 38, c = pc - r * 38;
        posi[nt] = pi;
        baseN[nt] = (r * 42 + c) * 136 + h * 16;
    }
    floatx16 acc[2];
#pragma unroll
    for (int nt = 0; nt < 2; ++nt)
#pragma unroll
        for (int i = 0; i < 16; ++i) acc[nt][i] = 0.f;

    for (int icc = 0; icc < 2; ++icc) {
        int ic0 = icc * 64;
        __syncthreads();
        // batched staging: 16 fixed slots per thread (3024 total, tail clamped)
#pragma unroll
        for (int half = 0; half < 2; ++half) {
            uint4 rb[8];
            int lo[8];
#pragma unroll
            for (int k = 0; k < 8; ++k) {
                int j = (half * 8 + k) * 192 + t;
                if (j > 3023) j -= 192;              // only k=7,half=1,t>=144
                int lr = j / 336, rem = j - lr * 336;
                int ix = rem >> 3, sb = rem & 7;
                int rg = row0 + lr; if (rg > 41) rg = 41;
                rb[k] = *(const uint4*)(h1n + ((((size_t)b * 42 + rg) * 42 + ix) * 128 + ic0 + sb * 8));
                lo[k] = (lr * 42 + ix) * 136 + sb * 16;
            }
#pragma unroll
            for (int k = 0; k < 8; ++k)
                *(uint4*)((char*)ins + lo[k]) = rb[k];
        }
        __syncthreads();
        const __bf16* wic = w2a + (size_t)icc * 25 * 4096 + mt * 512 + (lane << 3);
#pragma unroll
        for (int khw = 0; khw < 25; ++khw) {
            int kh = khw / 5, kw = khw - kh * 5;
            int doff = (kh * 42 + kw) * 136;
            const __bf16* wk = wic + khw * 4096;     // 4 ks x (2 mt) x 512
#pragma unroll
            for (int ks = 0; ks < 4; ++ks) {
                bf16x8 a0 = *(const bf16x8*)(wk + ks * 1024);
#pragma unroll
                for (int nt = 0; nt < 2; ++nt) {
                    bf16x8 bfr = *(const bf16x8*)((char*)ins + baseN[nt] + doff + ks * 32);
                    acc[nt] = __builtin_amdgcn_mfma_f32_32x32x16_bf16(a0, bfr, acc[nt], 0, 0, 0);
                }
            }
        }
    }
#pragma unroll
    for (int nt = 0; nt < 2; ++nt) {
        int pi = posi[nt];
        if (pi < validp) {
            int r = pi / 38, c = pi - r * 38;
            int oh = row0 + r;
            size_t obase = (((size_t)b * 38 + oh) * 38 + c) * 64;
#pragma unroll
            for (int g2 = 0; g2 < 4; ++g2) {
                int oc0 = mt * 32 + g2 * 8 + h * 4;
                float4 bv = *(const float4*)(b2 + oc0);
                bf16x4 pk;
                pk.x = (__bf16)(acc[nt][g2 * 4 + 0] + bv.x);
                pk.y = (__bf16)(acc[nt][g2 * 4 + 1] + bv.y);
                pk.z = (__bf16)(acc[nt][g2 * 4 + 2] + bv.z);
                pk.w = (__bf16)(acc[nt][g2 * 4 + 3] + bv.w);
                *(bf16x4*)(h2n + obase + oc0) = pk;
            }
        }
    }
}

// ---- caps conv 8x8 s2 via MFMA 32x32x16 + FUSED squash -> ub bf16 ---------
// Staging batched (6 fixed slots per thread, load-all-then-write-all).
__global__ __launch_bounds__(256, 4) void k_convcaps(const __bf16* __restrict__ h2n,
                                                     const __bf16* __restrict__ wca,
                                                     const float* __restrict__ bc,
                                                     __bf16* __restrict__ ub) {
    __shared__ __bf16 ins[13680];                    // 380 * 72 B = 27360 B
    int g = blockIdx.x, b = blockIdx.y;              // g in [0,8)
    int t = threadIdx.x;
    int lane = t & 63, ct = t >> 6;                  // wave = capsule type
    int c32 = lane & 31, h = lane >> 5;
    int rloc = c32 >> 4, cx = c32 & 15;

    floatx16 acc;
#pragma unroll
    for (int i = 0; i < 16; ++i) acc[i] = 0.f;

    int Bbase = (76 * rloc + cx) * 72 + h * 16;      // lane byte base in slab
    for (int icc = 0; icc < 2; ++icc) {
        int ic0 = icc * 32;
        __syncthreads();
        {
            uint4 rb[6];
            int lo[6];
#pragma unroll
            for (int k = 0; k < 6; ++k) {
                int j = k * 256 + t;
                if (j > 1519) j -= 256;              // only k=5, t>=240
                int r = j / 152, rem = j - r * 152;
                int c = rem >> 2, s = rem & 3;
                rb[k] = *(const uint4*)(h2n + ((((size_t)b * 38 + 4 * g + r) * 38 + c) * 64 + ic0 + s * 8));
                int X = (r * 2 + (c & 1)) * 19 + (c >> 1);
                lo[k] = X * 72 + s * 16;
            }
#pragma unroll
            for (int k = 0; k < 6; ++k)
                *(uint4*)((char*)ins + lo[k]) = rb[k];
        }
        __syncthreads();
        const __bf16* wic = wca + ((size_t)icc * 64 * 8 + ct) * 512 + (lane << 3);
#pragma unroll
        for (int khw = 0; khw < 64; ++khw) {
            int kh = khw >> 3, kw = khw & 7;
            int par = kw & 1, k2 = kw >> 1;
            int doff = ((kh * 2 + par) * 19 + k2) * 72;
            const __bf16* wk = wic + khw * 4096;     // 2 ks x 4 ct x 512
#pragma unroll
            for (int ks = 0; ks < 2; ++ks) {
                bf16x8 af = *(const bf16x8*)(wk + ks * 2048);
                bf16x8 bfr = *(const bf16x8*)((char*)ins + Bbase + doff + ks * 32);
                acc = __builtin_amdgcn_mfma_f32_32x32x16_bf16(af, bfr, acc, 0, 0, 0);
            }
        }
    }
    // fused bias + squash
    float vals[16];
    float n2p = 0.f;
#pragma unroll
    for (int g2 = 0; g2 < 4; ++g2) {
        float4 bv = *(const float4*)(bc + ct * 32 + g2 * 8 + h * 4);
#pragma unroll
        for (int j = 0; j < 4; ++j) {
            float v = acc[g2 * 4 + j] + ((const float*)&bv)[j];
            vals[g2 * 4 + j] = v;
            n2p = fmaf(v, v, n2p);
        }
    }
    float n2 = n2p + __shfl_xor(n2p, 32, 64);
    float scale = (n2 / (1.f + n2)) / sqrtf(n2 + EPSF);
    int pos = (2 * g + rloc) * 16 + cx;              // y*16 + x
    __bf16* dst = ub + (((size_t)b * 1024 + ct * 256 + pos) * 32);
#pragma unroll
    for (int g2 = 0; g2 < 4; ++g2) {
        bf16x4 pk;
        pk.x = (__bf16)(vals[g2 * 4 + 0] * scale);
        pk.y = (__bf16)(vals[g2 * 4 + 1] * scale);
        pk.z = (__bf16)(vals[g2 * 4 + 2] * scale);
        pk.w = (__bf16)(vals[g2 * 4 + 3] * scale);
        *(bf16x4*)(dst + g2 * 8 + h * 4) = pk;
    }
}

// ---- u_hat: ub bf16 [64,1024,32] x wrb bf16 [1024,10,16,32] -> uhT bf16 ---
__global__ __launch_bounds__(256, 2) void k_uhat(const __bf16* __restrict__ ub,
                                                 const __bf16* __restrict__ wrb,
                                                 __bf16* __restrict__ uhT) {
    int pt = blockIdx.x, ts = blockIdx.y, bz = blockIdx.z;
    int t = threadIdx.x;
    int p = pt * 64 + (t & 63);
    int q = t >> 6;
    bf16x8 wf[4][4];
#pragma unroll
    for (int o4 = 0; o4 < 4; ++o4)
#pragma unroll
        for (int j = 0; j < 4; ++j)
            wf[o4][j] = *(const bf16x8*)(wrb + (((size_t)p * 10 + ts) * 16 + q * 4 + o4) * 32 + j * 8);
#pragma unroll 1
    for (int bi = 0; bi < 16; ++bi) {
        int b = bz * 16 + bi;
        bf16x8 uf[4];
        const bf16x8* up = (const bf16x8*)(ub + ((size_t)b * 1024 + p) * 32);
#pragma unroll
        for (int j = 0; j < 4; ++j) uf[j] = up[j];
#pragma unroll
        for (int o4 = 0; o4 < 4; ++o4) {
            float s = 0.f;
#pragma unroll
            for (int j = 0; j < 4; ++j)
#pragma unroll
                for (int e = 0; e < 8; ++e)
                    s = fmaf((float)uf[j][e], (float)wf[o4][j][e], s);
            uhT[(((size_t)b * 10 + ts) * 16 + q * 4 + o4) * 1024 + p] = (__bf16)s;
        }
    }
}

// ---- routing: s = sum_p softmax(bl)_pt * u_hat ; v = squash(s) ------------
__global__ __launch_bounds__(256) void k_route_s(const __bf16* __restrict__ uhT,
                                                 const float* __restrict__ bl,
                                                 float* __restrict__ vout,
                                                 float* __restrict__ out,
                                                 int first, int last) {
    __shared__ float sred[4][16];
    int b = blockIdx.x, tt = blockIdx.y;
    int t = threadIdx.x;
    float acc[16];
#pragma unroll
    for (int o = 0; o < 16; ++o) acc[o] = 0.f;
    const float* blb = bl + b * 10240;
    const __bf16* uhb = uhT + ((size_t)b * 10 + tt) * 16384;
    for (int p = t; p < 1024; p += 256) {
        float c;
        if (first) {
            c = 0.1f;
        } else {
            float den = 0.f, et = 0.f;
#pragma unroll
            for (int tp = 0; tp < 10; ++tp) {
                float e = expf(blb[tp * 1024 + p]);
                den += e;
                if (tp == tt) et = e;
            }
            c = et / den;
        }
#pragma unroll
        for (int o = 0; o < 16; ++o)
            acc[o] = fmaf(c, (float)uhb[o * 1024 + p], acc[o]);
    }
    int lane = t & 63, wid = t >> 6;
#pragma unroll
    for (int o = 0; o < 16; ++o) {
        float v = acc[o];
#pragma unroll
        for (int off = 32; off >= 1; off >>= 1) v += __shfl_xor(v, off, 64);
        if (lane == 0) sred[wid][o] = v;
    }
    __syncthreads();
    if (t < 16) {
        float s = (sred[0][t] + sred[1][t]) + (sred[2][t] + sred[3][t]);
        float n2 = s * s;
#pragma unroll
        for (int off = 1; off < 16; off <<= 1) n2 += __shfl_xor(n2, off, 16);
        float scale = (n2 / (1.f + n2)) / sqrtf(n2 + EPSF);
        vout[(b * 10 + tt) * 16 + t] = s * scale;
        if (last && t == 0) {
            float sv2 = n2 * scale * scale;
            out[b * 10 + tt] = sqrtf(sv2 + EPSF);
        }
    }
}

// ---- routing: bl (+)= sum_o u_hat * v -------------------------------------
__global__ __launch_bounds__(256) void k_route_b(const __bf16* __restrict__ uhT,
                                                 const float* __restrict__ vv,
                                                 float* __restrict__ bl,
                                                 int first) {
    __shared__ float vs[16];
    int b = blockIdx.x, tt = blockIdx.y;
    int t = threadIdx.x;
    if (t < 16) vs[t] = vv[(b * 10 + tt) * 16 + t];
    __syncthreads();
    const __bf16* uhb = uhT + ((size_t)b * 10 + tt) * 16384;
    float* blb = bl + (b * 10 + tt) * 1024;
    for (int p = t; p < 1024; p += 256) {
        float d = 0.f;
#pragma unroll
        for (int o = 0; o < 16; ++o) d = fmaf((float)uhb[o * 1024 + p], vs[o], d);
        blb[p] = first ? d : (blb[p] + d);
    }
}

// ---------------------------------------------------------------------------
extern "C" void kernel_launch(void* const* d_in, const int* in_sizes, int n_in,
                              void* d_out, int out_size, void* d_ws, size_t ws_size,
                              hipStream_t stream) {
    const float* x  = (const float*)d_in[0];
    const float* w1 = (const float*)d_in[1];
    const float* b1 = (const float*)d_in[2];
    const float* w2 = (const float*)d_in[3];
    const float* b2 = (const float*)d_in[4];
    const float* wc = (const float*)d_in[5];
    const float* bc = (const float*)d_in[6];
    const float* Wr = (const float*)d_in[7];
    float* out = (float*)d_out;
    float* ws  = (float*)d_ws;

    // workspace layout (float offsets)
    __bf16* w2a = (__bf16*)(ws);                  // 204800 bf16
    __bf16* wca = (__bf16*)(ws + 102400);         // 524288 bf16
    __bf16* w1b = (__bf16*)(ws + 364544);         // 12288 bf16
    __bf16* h1n = (__bf16*)(ws + 375040);         // 14450688 bf16
    __bf16* h2n = (__bf16*)(ws + 7600384);        // 5914624 bf16
    __bf16* ub  = (__bf16*)(ws + 12654848);       // 2097152 bf16
    float*  bl  = ws + 14752000;                  // 655360 f
    float*  vv  = ws + 15407360;                  // 10240 f
    __bf16* wrb = (__bf16*)(ws + 15417600);       // 5242880 bf16
    __bf16* uhT = (__bf16*)(ws + 375040);         // overlays h1n (dead by k_uhat)

    k_t_w1b<<<48, 256, 0, stream>>>(w1, w1b);
    k_t_w2a<<<800, 256, 0, stream>>>(w2, w2a);
    k_t_wca<<<2048, 256, 0, stream>>>(wc, wca);
    k_t_wrb<<<20480, 256, 0, stream>>>(Wr, wrb);
    k_conv1_mfma<<<dim3(42, 2, 64), 256, 0, stream>>>(x, w1b, b1, h1n);
    k_conv2<<<dim3(8, 64, 2), 192, 0, stream>>>(h1n, w2a, b2, h2n);
    k_convcaps<<<dim3(8, 64), 256, 0, stream>>>(h2n, wca, bc, ub);
    k_uhat<<<dim3(16, 10, 4), 256, 0, stream>>>(ub, wrb, uhT);
    k_route_s<<<dim3(64, 10), 256, 0, stream>>>(uhT, bl, vv, out, 1, 0);
    k_route_b<<<dim3(64, 10), 256, 0, stream>>>(uhT, vv, bl, 1);
    k_route_s<<<dim3(64, 10), 256, 0, stream>>>(uhT, bl, vv, out, 0, 0);
    k_route_b<<<dim3(64, 10), 256, 0, stream>>>(uhT, vv, bl, 0);
    k_route_s<<<dim3(64, 10), 256, 0, stream>>>(uhT, bl, vv, out, 0, 1);
}

// Round 6
// 323.992 us; speedup vs baseline: 1.0620x; 1.0005x over previous
//
#include <hip/hip_runtime.h>
#include <hip/hip_bf16.h>
#include <math.h>

// ---------------------------------------------------------------------------
// GuoCapSAREncoder round 19: best-of-both recombination.
// Ladder evidence: conv2 time tracks (stage-phases x stage cost), not wave
// count: r13 (2 phases, 400 MFMA/phase/wave) = 87us; r17 icc-split (1 phase,
// 400) = ~68us; r18 mt-split (2 phases, 200) = 88us. So: conv2 = r17's
// icc-split EXACTLY (fp32 partials, 1024 blocks, one stage phase per block).
// The r17 regression was putting the p0+p1 reduction inside convcaps staging
// (+36us of latency-exposed fp32 fetch). Now a dedicated streaming reduce
// kernel does h2n = bf16(p0+p1+b2): 53MB coalesced at HBM rate ~= 11us.
// convcaps = r18's bf16 form EXACTLY (~45us). All components measured.
// ---------------------------------------------------------------------------

#define EPSF 1e-8f

typedef __bf16 bf16x8 __attribute__((ext_vector_type(8)));
typedef __bf16 bf16x4 __attribute__((ext_vector_type(4)));
typedef float floatx4 __attribute__((ext_vector_type(4)));
typedef float floatx16 __attribute__((ext_vector_type(16)));

// ---- weight transposes ----------------------------------------------------
__global__ __launch_bounds__(256) void k_t_w1b(const float* __restrict__ w1, __bf16* __restrict__ w1b) {
    int i = blockIdx.x * 256 + threadIdx.x;          // 12*128*8 = 12288
    if (i >= 12288) return;
    int kt = i >> 10, oc = (i >> 3) & 127, j = i & 7;
    int k = kt * 8 + j;
    w1b[i] = (__bf16)(k < 81 ? w1[oc * 81 + k] : 0.f);
}

// w2[oc64][ic128][khw25] -> w2a frag-ready: f = ((icc*25+khw)*4+ks)*2+mt,
// element [f][lane=h*32+c32][j] = w2[mt*32+c32][icc*64+ks*16+h*8+j][khw]
__global__ __launch_bounds__(256) void k_t_w2a(const float* __restrict__ w2, __bf16* __restrict__ w2a) {
    int i = blockIdx.x * 256 + threadIdx.x;          // 204800
    if (i >= 204800) return;
    int j = i & 7, lane = (i >> 3) & 63, f = i >> 9;
    int mt = f & 1, ks = (f >> 1) & 3, rem = f >> 3;
    int khw = rem % 25, icc = rem / 25;
    int c32 = lane & 31, h = lane >> 5;
    int oc = mt * 32 + c32;
    int ic = icc * 64 + ks * 16 + h * 8 + j;
    w2a[i] = (__bf16)w2[(oc * 128 + ic) * 25 + khw];
}

// wc[oc128][ic64][khw64] -> wca frag-ready: f = (((icc*64+khw)*2+ks)*4+ct,
// element [f][lane][j] = wc[ct*32+c32][icc*32+ks*16+h*8+j][khw]
__global__ __launch_bounds__(256) void k_t_wca(const float* __restrict__ wc, __bf16* __restrict__ wca) {
    int i = blockIdx.x * 256 + threadIdx.x;          // 524288
    if (i >= 524288) return;
    int j = i & 7, lane = (i >> 3) & 63, f = i >> 9;
    int ct = f & 3, ks = (f >> 2) & 1, khw = (f >> 3) & 63, icc = f >> 9;
    int c32 = lane & 31, h = lane >> 5;
    int oc = ct * 32 + c32;
    int ic = icc * 32 + ks * 16 + h * 8 + j;
    wca[i] = (__bf16)wc[(oc * 64 + ic) * 64 + khw];
}

__global__ __launch_bounds__(256) void k_t_wrb(const float* __restrict__ Wr, __bf16* __restrict__ wrb) {
    int i = blockIdx.x * 256 + threadIdx.x;          // 5242880
    if (i >= 5242880) return;
    wrb[i] = (__bf16)Wr[i];
}

// ---- conv1 9x9 + ReLU + maxpool2 via MFMA -> h1n NHWC bf16 [b][42][42][128]
__global__ __launch_bounds__(256, 3) void k_conv1_mfma(const float* __restrict__ x,
                                                       const __bf16* __restrict__ w1b,
                                                       const float* __restrict__ b1,
                                                       __bf16* __restrict__ h1n) {
    __shared__ float xs[960];                        // 10 rows x 92 fp32 (+pad)
    __shared__ __bf16 Bl[18432];                     // 12kt x 2row x 96pos x 8j
    int py = blockIdx.x, ocg = blockIdx.y, b = blockIdx.z;
    int t = threadIdx.x;
    int lane = t & 63, w = t >> 6;
    int cc = lane & 15, q = lane >> 4;

    const float* xb = x + (size_t)b * 8464 + 2 * py * 92;
    for (int j = t; j < 920; j += 256) xs[j] = xb[j];

    int ocA = ocg * 64 + w * 16 + cc;
    bf16x8 af[3];
#pragma unroll
    for (int ks = 0; ks < 3; ++ks)
        af[ks] = *(const bf16x8*)(w1b + ((ks * 4 + q) * 128 + ocA) * 8);

    __syncthreads();

    if (t < 192) {
        int row = t / 96, pos = t - (t / 96) * 96;
        int sbase = row * 92 + pos;
        bool pvalid = pos < 84;
#pragma unroll
        for (int kt = 0; kt < 12; ++kt) {
            bf16x8 pk;
#pragma unroll
            for (int j = 0; j < 8; ++j) {
                int k = kt * 8 + j;
                int kh = k / 9, kw = k - kh * 9;
                float v = (pvalid && k < 81) ? xs[sbase + kh * 92 + kw] : 0.f;
                pk[j] = (__bf16)v;
            }
            *(bf16x8*)(Bl + ((kt * 2 + row) * 96 + pos) * 8) = pk;
        }
    }
    __syncthreads();

    floatx4 acc[2][6];
    const char* Bb = (const char*)Bl + cc * 16 + q * 3072;
#pragma unroll
    for (int rr = 0; rr < 2; ++rr)
#pragma unroll
        for (int n6 = 0; n6 < 6; ++n6) {
            floatx4 a = (floatx4){0.f, 0.f, 0.f, 0.f};
#pragma unroll
            for (int ks = 0; ks < 3; ++ks) {
                bf16x8 bf = *(const bf16x8*)(Bb + ks * 12288 + rr * 1536 + n6 * 256);
                a = __builtin_amdgcn_mfma_f32_16x16x32_bf16(af[ks], bf, a, 0, 0, 0);
            }
            acc[rr][n6] = a;
        }

    int oc0 = ocg * 64 + w * 16 + q * 4;
    float4 bv = *(const float4*)(b1 + oc0);
    size_t obase = (((size_t)b * 42 + py) * 42) * 128 + oc0;
#pragma unroll
    for (int n6 = 0; n6 < 6; ++n6) {
        bf16x4 pk;
#pragma unroll
        for (int r = 0; r < 4; ++r) {
            float vert = fmaxf(acc[0][n6][r], acc[1][n6][r]);
            float hz = fmaxf(vert, __shfl_xor(vert, 1, 64));
            float pooled = fmaxf(hz + ((const float*)&bv)[r], 0.f);
            pk[r] = (__bf16)pooled;
        }
        if ((cc & 1) == 0) {
            int px = n6 * 8 + (cc >> 1);
            if (px < 42)
                *(bf16x4*)(h1n + obase + (size_t)px * 128) = pk;
        }
    }
}

// ---- conv2 5x5 via MFMA 32x32x16, icc-split: h1n -> fp32 partials ---------
// grid (8, 64, 2); block = r13 structure for ONE icc half; writes fp32
// partial (no bias) to p01 + icc*5914624, layout [b][38][38][64] f32.
__global__ __launch_bounds__(192, 2) void k_conv2(const __bf16* __restrict__ h1n,
                                                  const __bf16* __restrict__ w2a,
                                                  float* __restrict__ p01) {
    __shared__ __bf16 ins[25704];                    // 378 pos * 136 B = 51408 B
    int g = blockIdx.x, b = blockIdx.y, icc = blockIdx.z;
    int row0 = g * 5;
    int t = threadIdx.x;
    int lane = t & 63, w = t >> 6;                   // w in [0,3)
    int c32 = lane & 31, h = lane >> 5;
    int validp = (g < 7) ? 190 : 114;
    int ic0 = icc * 64;

    int baseN[2], posi[2];
#pragma unroll
    for (int nt = 0; nt < 2; ++nt) {
        int pi = (w * 2 + nt) * 32 + c32;
        int pc = pi < validp ? pi : validp - 1;
        int r = pc / 38, c = pc - r * 38;
        posi[nt] = pi;
        baseN[nt] = (r * 42 + c) * 136 + h * 16;
    }

    // batched staging: 16 fixed slots per thread (3024 total, tail clamped)
#pragma unroll
    for (int half = 0; half < 2; ++half) {
        uint4 rb[8];
        int lo[8];
#pragma unroll
        for (int k = 0; k < 8; ++k) {
            int j = (half * 8 + k) * 192 + t;
            if (j > 3023) j -= 192;                  // only k=7,half=1,t>=144
            int lr = j / 336, rem = j - lr * 336;
            int ix = rem >> 3, sb = rem & 7;
            int rg = row0 + lr; if (rg > 41) rg = 41;
            rb[k] = *(const uint4*)(h1n + ((((size_t)b * 42 + rg) * 42 + ix) * 128 + ic0 + sb * 8));
            lo[k] = (lr * 42 + ix) * 136 + sb * 16;
        }
#pragma unroll
        for (int k = 0; k < 8; ++k)
            *(uint4*)((char*)ins + lo[k]) = rb[k];
    }

    floatx16 acc[2][2];
#pragma unroll
    for (int mt = 0; mt < 2; ++mt)
#pragma unroll
        for (int nt = 0; nt < 2; ++nt)
#pragma unroll
            for (int i = 0; i < 16; ++i) acc[mt][nt][i] = 0.f;

    __syncthreads();
    const __bf16* wic = w2a + (size_t)icc * 25 * 4096 + (lane << 3);
#pragma unroll
    for (int khw = 0; khw < 25; ++khw) {
        int kh = khw / 5, kw = khw - kh * 5;
        int doff = (kh * 42 + kw) * 136;
        const __bf16* wk = wic + khw * 4096;         // 4 ks x 2 mt x 512
#pragma unroll
        for (int ks = 0; ks < 4; ++ks) {
            bf16x8 a0 = *(const bf16x8*)(wk + ks * 1024);
            bf16x8 a1 = *(const bf16x8*)(wk + ks * 1024 + 512);
#pragma unroll
            for (int nt = 0; nt < 2; ++nt) {
                bf16x8 bfr = *(const bf16x8*)((char*)ins + baseN[nt] + doff + ks * 32);
                acc[0][nt] = __builtin_amdgcn_mfma_f32_32x32x16_bf16(a0, bfr, acc[0][nt], 0, 0, 0);
                acc[1][nt] = __builtin_amdgcn_mfma_f32_32x32x16_bf16(a1, bfr, acc[1][nt], 0, 0, 0);
            }
        }
    }
    float* pdst = p01 + (size_t)icc * 5914624;
#pragma unroll
    for (int nt = 0; nt < 2; ++nt) {
        int pi = posi[nt];
        if (pi < validp) {
            int r = pi / 38, c = pi - r * 38;
            int oh = row0 + r;
            size_t obase = (((size_t)b * 38 + oh) * 38 + c) * 64;
#pragma unroll
            for (int mt = 0; mt < 2; ++mt) {
#pragma unroll
                for (int g2 = 0; g2 < 4; ++g2) {
                    int oc0 = mt * 32 + g2 * 8 + h * 4;
                    floatx4 pv;
                    pv[0] = acc[mt][nt][g2 * 4 + 0];
                    pv[1] = acc[mt][nt][g2 * 4 + 1];
                    pv[2] = acc[mt][nt][g2 * 4 + 2];
                    pv[3] = acc[mt][nt][g2 * 4 + 3];
                    *(floatx4*)(pdst + obase + oc0) = pv;
                }
            }
        }
    }
}

// ---- reduce: h2n = bf16(p0 + p1 + b2) -- pure streaming, HBM-rate ---------
__global__ __launch_bounds__(256) void k_reduce_h2(const float* __restrict__ p01,
                                                   const float* __restrict__ b2,
                                                   __bf16* __restrict__ h2n) {
    int i = blockIdx.x * 256 + threadIdx.x;          // 1478656 groups of 4
    if (i >= 1478656) return;
    size_t e = (size_t)i * 4;
    floatx4 a = *(const floatx4*)(p01 + e);
    floatx4 b = *(const floatx4*)(p01 + 5914624 + e);
    floatx4 bv = *(const floatx4*)(b2 + ((i * 4) & 63));
    bf16x4 pk;
    pk.x = (__bf16)(a[0] + b[0] + bv[0]);
    pk.y = (__bf16)(a[1] + b[1] + bv[1]);
    pk.z = (__bf16)(a[2] + b[2] + bv[2]);
    pk.w = (__bf16)(a[3] + b[3] + bv[3]);
    *(bf16x4*)(h2n + e) = pk;
}

// ---- caps conv 8x8 s2 via MFMA 32x32x16 + FUSED squash -> ub bf16 ---------
// Staging batched (6 fixed slots per thread, load-all-then-write-all).
__global__ __launch_bounds__(256, 4) void k_convcaps(const __bf16* __restrict__ h2n,
                                                     const __bf16* __restrict__ wca,
                                                     const float* __restrict__ bc,
                                                     __bf16* __restrict__ ub) {
    __shared__ __bf16 ins[13680];                    // 380 * 72 B = 27360 B
    int g = blockIdx.x, b = blockIdx.y;              // g in [0,8)
    int t = threadIdx.x;
    int lane = t & 63, ct = t >> 6;                  // wave = capsule type
    int c32 = lane & 31, h = lane >> 5;
    int rloc = c32 >> 4, cx = c32 & 15;

    floatx16 acc;
#pragma unroll
    for (int i = 0; i < 16; ++i) acc[i] = 0.f;

    int Bbase = (76 * rloc + cx) * 72 + h * 16;      // lane byte base in slab
    for (int icc = 0; icc < 2; ++icc) {
        int ic0 = icc * 32;
        __syncthreads();
        {
            uint4 rb[6];
            int lo[6];
#pragma unroll
            for (int k = 0; k < 6; ++k) {
                int j = k * 256 + t;
                if (j > 1519) j -= 256;              // only k=5, t>=240
                int r = j / 152, rem = j - r * 152;
                int c = rem >> 2, s = rem & 3;
                rb[k] = *(const uint4*)(h2n + ((((size_t)b * 38 + 4 * g + r) * 38 + c) * 64 + ic0 + s * 8));
                int X = (r * 2 + (c & 1)) * 19 + (c >> 1);
                lo[k] = X * 72 + s * 16;
            }
#pragma unroll
            for (int k = 0; k < 6; ++k)
                *(uint4*)((char*)ins + lo[k]) = rb[k];
        }
        __syncthreads();
        const __bf16* wic = wca + ((size_t)icc * 64 * 8 + ct) * 512 + (lane << 3);
#pragma unroll
        for (int khw = 0; khw < 64; ++khw) {
            int kh = khw >> 3, kw = khw & 7;
            int par = kw & 1, k2 = kw >> 1;
            int doff = ((kh * 2 + par) * 19 + k2) * 72;
            const __bf16* wk = wic + khw * 4096;     // 2 ks x 4 ct x 512
#pragma unroll
            for (int ks = 0; ks < 2; ++ks) {
                bf16x8 af = *(const bf16x8*)(wk + ks * 2048);
                bf16x8 bfr = *(const bf16x8*)((char*)ins + Bbase + doff + ks * 32);
                acc = __builtin_amdgcn_mfma_f32_32x32x16_bf16(af, bfr, acc, 0, 0, 0);
            }
        }
    }
    // fused bias + squash
    float vals[16];
    float n2p = 0.f;
#pragma unroll
    for (int g2 = 0; g2 < 4; ++g2) {
        float4 bv = *(const float4*)(bc + ct * 32 + g2 * 8 + h * 4);
#pragma unroll
        for (int j = 0; j < 4; ++j) {
            float v = acc[g2 * 4 + j] + ((const float*)&bv)[j];
            vals[g2 * 4 + j] = v;
            n2p = fmaf(v, v, n2p);
        }
    }
    float n2 = n2p + __shfl_xor(n2p, 32, 64);
    float scale = (n2 / (1.f + n2)) / sqrtf(n2 + EPSF);
    int pos = (2 * g + rloc) * 16 + cx;              // y*16 + x
    __bf16* dst = ub + (((size_t)b * 1024 + ct * 256 + pos) * 32);
#pragma unroll
    for (int g2 = 0; g2 < 4; ++g2) {
        bf16x4 pk;
        pk.x = (__bf16)(vals[g2 * 4 + 0] * scale);
        pk.y = (__bf16)(vals[g2 * 4 + 1] * scale);
        pk.z = (__bf16)(vals[g2 * 4 + 2] * scale);
        pk.w = (__bf16)(vals[g2 * 4 + 3] * scale);
        *(bf16x4*)(dst + g2 * 8 + h * 4) = pk;
    }
}

// ---- u_hat: ub bf16 [64,1024,32] x wrb bf16 [1024,10,16,32] -> uhT bf16 ---
__global__ __launch_bounds__(256, 2) void k_uhat(const __bf16* __restrict__ ub,
                                                 const __bf16* __restrict__ wrb,
                                                 __bf16* __restrict__ uhT) {
    int pt = blockIdx.x, ts = blockIdx.y, bz = blockIdx.z;
    int t = threadIdx.x;
    int p = pt * 64 + (t & 63);
    int q = t >> 6;
    bf16x8 wf[4][4];
#pragma unroll
    for (int o4 = 0; o4 < 4; ++o4)
#pragma unroll
        for (int j = 0; j < 4; ++j)
            wf[o4][j] = *(const bf16x8*)(wrb + (((size_t)p * 10 + ts) * 16 + q * 4 + o4) * 32 + j * 8);
#pragma unroll 1
    for (int bi = 0; bi < 16; ++bi) {
        int b = bz * 16 + bi;
        bf16x8 uf[4];
        const bf16x8* up = (const bf16x8*)(ub + ((size_t)b * 1024 + p) * 32);
#pragma unroll
        for (int j = 0; j < 4; ++j) uf[j] = up[j];
#pragma unroll
        for (int o4 = 0; o4 < 4; ++o4) {
            float s = 0.f;
#pragma unroll
            for (int j = 0; j < 4; ++j)
#pragma unroll
                for (int e = 0; e < 8; ++e)
                    s = fmaf((float)uf[j][e], (float)wf[o4][j][e], s);
            uhT[(((size_t)b * 10 + ts) * 16 + q * 4 + o4) * 1024 + p] = (__bf16)s;
        }
    }
}

// ---- routing: s = sum_p softmax(bl)_pt * u_hat ; v = squash(s) ------------
__global__ __launch_bounds__(256) void k_route_s(const __bf16* __restrict__ uhT,
                                                 const float* __restrict__ bl,
                                                 float* __restrict__ vout,
                                                 float* __restrict__ out,
                                                 int first, int last) {
    __shared__ float sred[4][16];
    int b = blockIdx.x, tt = blockIdx.y;
    int t = threadIdx.x;
    float acc[16];
#pragma unroll
    for (int o = 0; o < 16; ++o) acc[o] = 0.f;
    const float* blb = bl + b * 10240;
    const __bf16* uhb = uhT + ((size_t)b * 10 + tt) * 16384;
    for (int p = t; p < 1024; p += 256) {
        float c;
        if (first) {
            c = 0.1f;
        } else {
            float den = 0.f, et = 0.f;
#pragma unroll
            for (int tp = 0; tp < 10; ++tp) {
                float e = expf(blb[tp * 1024 + p]);
                den += e;
                if (tp == tt) et = e;
            }
            c = et / den;
        }
#pragma unroll
        for (int o = 0; o < 16; ++o)
            acc[o] = fmaf(c, (float)uhb[o * 1024 + p], acc[o]);
    }
    int lane = t & 63, wid = t >> 6;
#pragma unroll
    for (int o = 0; o < 16; ++o) {
        float v = acc[o];
#pragma unroll
        for (int off = 32; off >= 1; off >>= 1) v += __shfl_xor(v, off, 64);
        if (lane == 0) sred[wid][o] = v;
    }
    __syncthreads();
    if (t < 16) {
        float s = (sred[0][t] + sred[1][t]) + (sred[2][t] + sred[3][t]);
        float n2 = s * s;
#pragma unroll
        for (int off = 1; off < 16; off <<= 1) n2 += __shfl_xor(n2, off, 16);
        float scale = (n2 / (1.f + n2)) / sqrtf(n2 + EPSF);
        vout[(b * 10 + tt) * 16 + t] = s * scale;
        if (last && t == 0) {
            float sv2 = n2 * scale * scale;
            out[b * 10 + tt] = sqrtf(sv2 + EPSF);
        }
    }
}

// ---- routing: bl (+)= sum_o u_hat * v -------------------------------------
__global__ __launch_bounds__(256) void k_route_b(const __bf16* __restrict__ uhT,
                                                 const float* __restrict__ vv,
                                                 float* __restrict__ bl,
                                                 int first) {
    __shared__ float vs[16];
    int b = blockIdx.x, tt = blockIdx.y;
    int t = threadIdx.x;
    if (t < 16) vs[t] = vv[(b * 10 + tt) * 16 + t];
    __syncthreads();
    const __bf16* uhb = uhT + ((size_t)b * 10 + tt) * 16384;
    float* blb = bl + (b * 10 + tt) * 1024;
    for (int p = t; p < 1024; p += 256) {
        float d = 0.f;
#pragma unroll
        for (int o = 0; o < 16; ++o) d = fmaf((float)uhb[o * 1024 + p], vs[o], d);
        blb[p] = first ? d : (blb[p] + d);
    }
}

// ---------------------------------------------------------------------------
extern "C" void kernel_launch(void* const* d_in, const int* in_sizes, int n_in,
                              void* d_out, int out_size, void* d_ws, size_t ws_size,
                              hipStream_t stream) {
    const float* x  = (const float*)d_in[0];
    const float* w1 = (const float*)d_in[1];
    const float* b1 = (const float*)d_in[2];
    const float* w2 = (const float*)d_in[3];
    const float* b2 = (const float*)d_in[4];
    const float* wc = (const float*)d_in[5];
    const float* bc = (const float*)d_in[6];
    const float* Wr = (const float*)d_in[7];
    float* out = (float*)d_out;
    float* ws  = (float*)d_ws;

    // workspace layout (float offsets)
    __bf16* w2a = (__bf16*)(ws);                  // 204800 bf16
    __bf16* wca = (__bf16*)(ws + 102400);         // 524288 bf16
    __bf16* w1b = (__bf16*)(ws + 364544);         // 12288 bf16
    __bf16* h1n = (__bf16*)(ws + 375040);         // 14450688 bf16
    __bf16* h2n = (__bf16*)(ws + 7600384);        // 5914624 bf16
    __bf16* ub  = (__bf16*)(ws + 12654848);       // 2097152 bf16
    float*  bl  = ws + 14752000;                  // 655360 f
    float*  vv  = ws + 15407360;                  // 10240 f
    __bf16* wrb = (__bf16*)(ws + 15417600);       // 5242880 bf16
    float*  p01 = ws + 18039040;                  // 2 x 5914624 f32 partials
    __bf16* uhT = (__bf16*)(ws + 375040);         // overlays h1n (dead by k_uhat)

    k_t_w1b<<<48, 256, 0, stream>>>(w1, w1b);
    k_t_w2a<<<800, 256, 0, stream>>>(w2, w2a);
    k_t_wca<<<2048, 256, 0, stream>>>(wc, wca);
    k_t_wrb<<<20480, 256, 0, stream>>>(Wr, wrb);
    k_conv1_mfma<<<dim3(42, 2, 64), 256, 0, stream>>>(x, w1b, b1, h1n);
    k_conv2<<<dim3(8, 64, 2), 192, 0, stream>>>(h1n, w2a, p01);
    k_reduce_h2<<<5776, 256, 0, stream>>>(p01, b2, h2n);
    k_convcaps<<<dim3(8, 64), 256, 0, stream>>>(h2n, wca, bc, ub);
    k_uhat<<<dim3(16, 10, 4), 256, 0, stream>>>(ub, wrb, uhT);
    k_route_s<<<dim3(64, 10), 256, 0, stream>>>(uhT, bl, vv, out, 1, 0);
    k_route_b<<<dim3(64, 10), 256, 0, stream>>>(uhT, vv, bl, 1);
    k_route_s<<<dim3(64, 10), 256, 0, stream>>>(uhT, bl, vv, out, 0, 0);
    k_route_b<<<dim3(64, 10), 256, 0, stream>>>(uhT, vv, bl, 0);
    k_route_s<<<dim3(64, 10), 256, 0, stream>>>(uhT, bl, vv, out, 0, 1);
}

// Round 8
// 315.221 us; speedup vs baseline: 1.0916x; 1.0278x over previous
//
#include <hip/hip_runtime.h>
#include <hip/hip_bf16.h>
#include <math.h>

// ---------------------------------------------------------------------------
// GuoCapSAREncoder round 21: r20's routing fusion + RACE FIX via bl
// ping-pong. r20 fused [s+b] but b-phase wrote bl[b][tt] while sibling
// blocks' s-phase still needed to read it (the unfused version had a
// device-sync between) -> post-timing divergence. Now: s-phase reads blR,
// b-phase writes blW (different buffer): L1 writes blA; L2 reads blA,
// writes blB=blA+d; L3 reads blB. Race-free, arithmetic identical to r19's
// 5-kernel sequence, same work every call (graph-safe). uhT still staged
// once into 32KB LDS per block serving both phases. All compute kernels
// frozen from r19 (conv2 icc-split 70.5us measured, total 324.0).
// ---------------------------------------------------------------------------

#define EPSF 1e-8f

typedef __bf16 bf16x8 __attribute__((ext_vector_type(8)));
typedef __bf16 bf16x4 __attribute__((ext_vector_type(4)));
typedef float floatx4 __attribute__((ext_vector_type(4)));
typedef float floatx16 __attribute__((ext_vector_type(16)));

// ---- weight transposes ----------------------------------------------------
__global__ __launch_bounds__(256) void k_t_w1b(const float* __restrict__ w1, __bf16* __restrict__ w1b) {
    int i = blockIdx.x * 256 + threadIdx.x;          // 12*128*8 = 12288
    if (i >= 12288) return;
    int kt = i >> 10, oc = (i >> 3) & 127, j = i & 7;
    int k = kt * 8 + j;
    w1b[i] = (__bf16)(k < 81 ? w1[oc * 81 + k] : 0.f);
}

// w2[oc64][ic128][khw25] -> w2a frag-ready: f = ((icc*25+khw)*4+ks)*2+mt,
// element [f][lane=h*32+c32][j] = w2[mt*32+c32][icc*64+ks*16+h*8+j][khw]
__global__ __launch_bounds__(256) void k_t_w2a(const float* __restrict__ w2, __bf16* __restrict__ w2a) {
    int i = blockIdx.x * 256 + threadIdx.x;          // 204800
    if (i >= 204800) return;
    int j = i & 7, lane = (i >> 3) & 63, f = i >> 9;
    int mt = f & 1, ks = (f >> 1) & 3, rem = f >> 3;
    int khw = rem % 25, icc = rem / 25;
    int c32 = lane & 31, h = lane >> 5;
    int oc = mt * 32 + c32;
    int ic = icc * 64 + ks * 16 + h * 8 + j;
    w2a[i] = (__bf16)w2[(oc * 128 + ic) * 25 + khw];
}

// wc[oc128][ic64][khw64] -> wca frag-ready: f = (((icc*64+khw)*2+ks)*4+ct,
// element [f][lane][j] = wc[ct*32+c32][icc*32+ks*16+h*8+j][khw]
__global__ __launch_bounds__(256) void k_t_wca(const float* __restrict__ wc, __bf16* __restrict__ wca) {
    int i = blockIdx.x * 256 + threadIdx.x;          // 524288
    if (i >= 524288) return;
    int j = i & 7, lane = (i >> 3) & 63, f = i >> 9;
    int ct = f & 3, ks = (f >> 2) & 1, khw = (f >> 3) & 63, icc = f >> 9;
    int c32 = lane & 31, h = lane >> 5;
    int oc = ct * 32 + c32;
    int ic = icc * 32 + ks * 16 + h * 8 + j;
    wca[i] = (__bf16)wc[(oc * 64 + ic) * 64 + khw];
}

__global__ __launch_bounds__(256) void k_t_wrb(const float* __restrict__ Wr, __bf16* __restrict__ wrb) {
    int i = blockIdx.x * 256 + threadIdx.x;          // 5242880
    if (i >= 5242880) return;
    wrb[i] = (__bf16)Wr[i];
}

// ---- conv1 9x9 + ReLU + maxpool2 via MFMA -> h1n NHWC bf16 [b][42][42][128]
__global__ __launch_bounds__(256, 3) void k_conv1_mfma(const float* __restrict__ x,
                                                       const __bf16* __restrict__ w1b,
                                                       const float* __restrict__ b1,
                                                       __bf16* __restrict__ h1n) {
    __shared__ float xs[960];                        // 10 rows x 92 fp32 (+pad)
    __shared__ __bf16 Bl[18432];                     // 12kt x 2row x 96pos x 8j
    int py = blockIdx.x, ocg = blockIdx.y, b = blockIdx.z;
    int t = threadIdx.x;
    int lane = t & 63, w = t >> 6;
    int cc = lane & 15, q = lane >> 4;

    const float* xb = x + (size_t)b * 8464 + 2 * py * 92;
    for (int j = t; j < 920; j += 256) xs[j] = xb[j];

    int ocA = ocg * 64 + w * 16 + cc;
    bf16x8 af[3];
#pragma unroll
    for (int ks = 0; ks < 3; ++ks)
        af[ks] = *(const bf16x8*)(w1b + ((ks * 4 + q) * 128 + ocA) * 8);

    __syncthreads();

    if (t < 192) {
        int row = t / 96, pos = t - (t / 96) * 96;
        int sbase = row * 92 + pos;
        bool pvalid = pos < 84;
#pragma unroll
        for (int kt = 0; kt < 12; ++kt) {
            bf16x8 pk;
#pragma unroll
            for (int j = 0; j < 8; ++j) {
                int k = kt * 8 + j;
                int kh = k / 9, kw = k - kh * 9;
                float v = (pvalid && k < 81) ? xs[sbase + kh * 92 + kw] : 0.f;
                pk[j] = (__bf16)v;
            }
            *(bf16x8*)(Bl + ((kt * 2 + row) * 96 + pos) * 8) = pk;
        }
    }
    __syncthreads();

    floatx4 acc[2][6];
    const char* Bb = (const char*)Bl + cc * 16 + q * 3072;
#pragma unroll
    for (int rr = 0; rr < 2; ++rr)
#pragma unroll
        for (int n6 = 0; n6 < 6; ++n6) {
            floatx4 a = (floatx4){0.f, 0.f, 0.f, 0.f};
#pragma unroll
            for (int ks = 0; ks < 3; ++ks) {
                bf16x8 bf = *(const bf16x8*)(Bb + ks * 12288 + rr * 1536 + n6 * 256);
                a = __builtin_amdgcn_mfma_f32_16x16x32_bf16(af[ks], bf, a, 0, 0, 0);
            }
            acc[rr][n6] = a;
        }

    int oc0 = ocg * 64 + w * 16 + q * 4;
    float4 bv = *(const float4*)(b1 + oc0);
    size_t obase = (((size_t)b * 42 + py) * 42) * 128 + oc0;
#pragma unroll
    for (int n6 = 0; n6 < 6; ++n6) {
        bf16x4 pk;
#pragma unroll
        for (int r = 0; r < 4; ++r) {
            float vert = fmaxf(acc[0][n6][r], acc[1][n6][r]);
            float hz = fmaxf(vert, __shfl_xor(vert, 1, 64));
            float pooled = fmaxf(hz + ((const float*)&bv)[r], 0.f);
            pk[r] = (__bf16)pooled;
        }
        if ((cc & 1) == 0) {
            int px = n6 * 8 + (cc >> 1);
            if (px < 42)
                *(bf16x4*)(h1n + obase + (size_t)px * 128) = pk;
        }
    }
}

// ---- conv2 5x5 via MFMA 32x32x16, icc-split: h1n -> fp32 partials ---------
// grid (8, 64, 2); block = r13 structure for ONE icc half; writes fp32
// partial (no bias) to p01 + icc*5914624, layout [b][38][38][64] f32.
__global__ __launch_bounds__(192, 2) void k_conv2(const __bf16* __restrict__ h1n,
                                                  const __bf16* __restrict__ w2a,
                                                  float* __restrict__ p01) {
    __shared__ __bf16 ins[25704];                    // 378 pos * 136 B = 51408 B
    int g = blockIdx.x, b = blockIdx.y, icc = blockIdx.z;
    int row0 = g * 5;
    int t = threadIdx.x;
    int lane = t & 63, w = t >> 6;                   // w in [0,3)
    int c32 = lane & 31, h = lane >> 5;
    int validp = (g < 7) ? 190 : 114;
    int ic0 = icc * 64;

    int baseN[2], posi[2];
#pragma unroll
    for (int nt = 0; nt < 2; ++nt) {
        int pi = (w * 2 + nt) * 32 + c32;
        int pc = pi < validp ? pi : validp - 1;
        int r = pc / 38, c = pc - r * 38;
        posi[nt] = pi;
        baseN[nt] = (r * 42 + c) * 136 + h * 16;
    }

    // batched staging: 16 fixed slots per thread (3024 total, tail clamped)
#pragma unroll
    for (int half = 0; half < 2; ++half) {
        uint4 rb[8];
        int lo[8];
#pragma unroll
        for (int k = 0; k < 8; ++k) {
            int j = (half * 8 + k) * 192 + t;
            if (j > 3023) j -= 192;                  // only k=7,half=1,t>=144
            int lr = j / 336, rem = j - lr * 336;
            int ix = rem >> 3, sb = rem & 7;
            int rg = row0 + lr; if (rg > 41) rg = 41;
            rb[k] = *(const uint4*)(h1n + ((((size_t)b * 42 + rg) * 42 + ix) * 128 + ic0 + sb * 8));
            lo[k] = (lr * 42 + ix) * 136 + sb * 16;
        }
#pragma unroll
        for (int k = 0; k < 8; ++k)
            *(uint4*)((char*)ins + lo[k]) = rb[k];
    }

    floatx16 acc[2][2];
#pragma unroll
    for (int mt = 0; mt < 2; ++mt)
#pragma unroll
        for (int nt = 0; nt < 2; ++nt)
#pragma unroll
            for (int i = 0; i < 16; ++i) acc[mt][nt][i] = 0.f;

    __syncthreads();
    const __bf16* wic = w2a + (size_t)icc * 25 * 4096 + (lane << 3);
#pragma unroll
    for (int khw = 0; khw < 25; ++khw) {
        int kh = khw / 5, kw = khw - kh * 5;
        int doff = (kh * 42 + kw) * 136;
        const __bf16* wk = wic + khw * 4096;         // 4 ks x 2 mt x 512
#pragma unroll
        for (int ks = 0; ks < 4; ++ks) {
            bf16x8 a0 = *(const bf16x8*)(wk + ks * 1024);
            bf16x8 a1 = *(const bf16x8*)(wk + ks * 1024 + 512);
#pragma unroll
            for (int nt = 0; nt < 2; ++nt) {
                bf16x8 bfr = *(const bf16x8*)((char*)ins + baseN[nt] + doff + ks * 32);
                acc[0][nt] = __builtin_amdgcn_mfma_f32_32x32x16_bf16(a0, bfr, acc[0][nt], 0, 0, 0);
                acc[1][nt] = __builtin_amdgcn_mfma_f32_32x32x16_bf16(a1, bfr, acc[1][nt], 0, 0, 0);
            }
        }
    }
    float* pdst = p01 + (size_t)icc * 5914624;
#pragma unroll
    for (int nt = 0; nt < 2; ++nt) {
        int pi = posi[nt];
        if (pi < validp) {
            int r = pi / 38, c = pi - r * 38;
            int oh = row0 + r;
            size_t obase = (((size_t)b * 38 + oh) * 38 + c) * 64;
#pragma unroll
            for (int mt = 0; mt < 2; ++mt) {
#pragma unroll
                for (int g2 = 0; g2 < 4; ++g2) {
                    int oc0 = mt * 32 + g2 * 8 + h * 4;
                    floatx4 pv;
                    pv[0] = acc[mt][nt][g2 * 4 + 0];
                    pv[1] = acc[mt][nt][g2 * 4 + 1];
                    pv[2] = acc[mt][nt][g2 * 4 + 2];
                    pv[3] = acc[mt][nt][g2 * 4 + 3];
                    *(floatx4*)(pdst + obase + oc0) = pv;
                }
            }
        }
    }
}

// ---- reduce: h2n = bf16(p0 + p1 + b2) -- pure streaming, HBM-rate ---------
__global__ __launch_bounds__(256) void k_reduce_h2(const float* __restrict__ p01,
                                                   const float* __restrict__ b2,
                                                   __bf16* __restrict__ h2n) {
    int i = blockIdx.x * 256 + threadIdx.x;          // 1478656 groups of 4
    if (i >= 1478656) return;
    size_t e = (size_t)i * 4;
    floatx4 a = *(const floatx4*)(p01 + e);
    floatx4 b = *(const floatx4*)(p01 + 5914624 + e);
    floatx4 bv = *(const floatx4*)(b2 + ((i * 4) & 63));
    bf16x4 pk;
    pk.x = (__bf16)(a[0] + b[0] + bv[0]);
    pk.y = (__bf16)(a[1] + b[1] + bv[1]);
    pk.z = (__bf16)(a[2] + b[2] + bv[2]);
    pk.w = (__bf16)(a[3] + b[3] + bv[3]);
    *(bf16x4*)(h2n + e) = pk;
}

// ---- caps conv 8x8 s2 via MFMA 32x32x16 + FUSED squash -> ub bf16 ---------
// Staging batched (6 fixed slots per thread, load-all-then-write-all).
__global__ __launch_bounds__(256, 4) void k_convcaps(const __bf16* __restrict__ h2n,
                                                     const __bf16* __restrict__ wca,
                                                     const float* __restrict__ bc,
                                                     __bf16* __restrict__ ub) {
    __shared__ __bf16 ins[13680];                    // 380 * 72 B = 27360 B
    int g = blockIdx.x, b = blockIdx.y;              // g in [0,8)
    int t = threadIdx.x;
    int lane = t & 63, ct = t >> 6;                  // wave = capsule type
    int c32 = lane & 31, h = lane >> 5;
    int rloc = c32 >> 4, cx = c32 & 15;

    floatx16 acc;
#pragma unroll
    for (int i = 0; i < 16; ++i) acc[i] = 0.f;

    int Bbase = (76 * rloc + cx) * 72 + h * 16;      // lane byte base in slab
    for (int icc = 0; icc < 2; ++icc) {
        int ic0 = icc * 32;
        __syncthreads();
        {
            uint4 rb[6];
            int lo[6];
#pragma unroll
            for (int k = 0; k < 6; ++k) {
                int j = k * 256 + t;
                if (j > 1519) j -= 256;              // only k=5, t>=240
                int r = j / 152, rem = j - r * 152;
                int c = rem >> 2, s = rem & 3;
                rb[k] = *(const uint4*)(h2n + ((((size_t)b * 38 + 4 * g + r) * 38 + c) * 64 + ic0 + s * 8));
                int X = (r * 2 + (c & 1)) * 19 + (c >> 1);
                lo[k] = X * 72 + s * 16;
            }
#pragma unroll
            for (int k = 0; k < 6; ++k)
                *(uint4*)((char*)ins + lo[k]) = rb[k];
        }
        __syncthreads();
        const __bf16* wic = wca + ((size_t)icc * 64 * 8 + ct) * 512 + (lane << 3);
#pragma unroll
        for (int khw = 0; khw < 64; ++khw) {
            int kh = khw >> 3, kw = khw & 7;
            int par = kw & 1, k2 = kw >> 1;
            int doff = ((kh * 2 + par) * 19 + k2) * 72;
            const __bf16* wk = wic + khw * 4096;     // 2 ks x 4 ct x 512
#pragma unroll
            for (int ks = 0; ks < 2; ++ks) {
                bf16x8 af = *(const bf16x8*)(wk + ks * 2048);
                bf16x8 bfr = *(const bf16x8*)((char*)ins + Bbase + doff + ks * 32);
                acc = __builtin_amdgcn_mfma_f32_32x32x16_bf16(af, bfr, acc, 0, 0, 0);
            }
        }
    }
    // fused bias + squash
    float vals[16];
    float n2p = 0.f;
#pragma unroll
    for (int g2 = 0; g2 < 4; ++g2) {
        float4 bv = *(const float4*)(bc + ct * 32 + g2 * 8 + h * 4);
#pragma unroll
        for (int j = 0; j < 4; ++j) {
            float v = acc[g2 * 4 + j] + ((const float*)&bv)[j];
            vals[g2 * 4 + j] = v;
            n2p = fmaf(v, v, n2p);
        }
    }
    float n2 = n2p + __shfl_xor(n2p, 32, 64);
    float scale = (n2 / (1.f + n2)) / sqrtf(n2 + EPSF);
    int pos = (2 * g + rloc) * 16 + cx;              // y*16 + x
    __bf16* dst = ub + (((size_t)b * 1024 + ct * 256 + pos) * 32);
#pragma unroll
    for (int g2 = 0; g2 < 4; ++g2) {
        bf16x4 pk;
        pk.x = (__bf16)(vals[g2 * 4 + 0] * scale);
        pk.y = (__bf16)(vals[g2 * 4 + 1] * scale);
        pk.z = (__bf16)(vals[g2 * 4 + 2] * scale);
        pk.w = (__bf16)(vals[g2 * 4 + 3] * scale);
        *(bf16x4*)(dst + g2 * 8 + h * 4) = pk;
    }
}

// ---- u_hat: ub bf16 [64,1024,32] x wrb bf16 [1024,10,16,32] -> uhT bf16 ---
__global__ __launch_bounds__(256, 2) void k_uhat(const __bf16* __restrict__ ub,
                                                 const __bf16* __restrict__ wrb,
                                                 __bf16* __restrict__ uhT) {
    int pt = blockIdx.x, ts = blockIdx.y, bz = blockIdx.z;
    int t = threadIdx.x;
    int p = pt * 64 + (t & 63);
    int q = t >> 6;
    bf16x8 wf[4][4];
#pragma unroll
    for (int o4 = 0; o4 < 4; ++o4)
#pragma unroll
        for (int j = 0; j < 4; ++j)
            wf[o4][j] = *(const bf16x8*)(wrb + (((size_t)p * 10 + ts) * 16 + q * 4 + o4) * 32 + j * 8);
#pragma unroll 1
    for (int bi = 0; bi < 16; ++bi) {
        int b = bz * 16 + bi;
        bf16x8 uf[4];
        const bf16x8* up = (const bf16x8*)(ub + ((size_t)b * 1024 + p) * 32);
#pragma unroll
        for (int j = 0; j < 4; ++j) uf[j] = up[j];
#pragma unroll
        for (int o4 = 0; o4 < 4; ++o4) {
            float s = 0.f;
#pragma unroll
            for (int j = 0; j < 4; ++j)
#pragma unroll
                for (int e = 0; e < 8; ++e)
                    s = fmaf((float)uf[j][e], (float)wf[o4][j][e], s);
            uhT[(((size_t)b * 10 + ts) * 16 + q * 4 + o4) * 1024 + p] = (__bf16)s;
        }
    }
}

// ---- fused routing step with bl ping-pong ---------------------------------
// Block (b,tt): stages 16x1024 bf16 uhT slice into 32KB LDS once; s-phase
// reads blR (stable this launch), b-phase writes blW (disjoint buffer) ->
// race-free. Arithmetic identical to the unfused 5-kernel sequence.
__global__ __launch_bounds__(256) void k_route(const __bf16* __restrict__ uhT,
                                               const float* __restrict__ blR,
                                               float* __restrict__ blW,
                                               float* __restrict__ out,
                                               int first, int dob, int last) {
    __shared__ __bf16 uh_s[16384];                   // 32 KB: [o][p]
    __shared__ float sred[4][16];
    __shared__ float vs[16];
    int b = blockIdx.x, tt = blockIdx.y;
    int t = threadIdx.x;
    const __bf16* uhb = uhT + ((size_t)b * 10 + tt) * 16384;
#pragma unroll
    for (int k = 0; k < 8; ++k) {
        int j = k * 256 + t;
        *(uint4*)((char*)uh_s + j * 16) = *(const uint4*)((const char*)uhb + j * 16);
    }
    __syncthreads();

    // ---- s-phase
    float acc[16];
#pragma unroll
    for (int o = 0; o < 16; ++o) acc[o] = 0.f;
    const float* blb = blR + b * 10240;
    for (int p = t; p < 1024; p += 256) {
        float c;
        if (first) {
            c = 0.1f;
        } else {
            float den = 0.f, et = 0.f;
#pragma unroll
            for (int tp = 0; tp < 10; ++tp) {
                float e = expf(blb[tp * 1024 + p]);
                den += e;
                if (tp == tt) et = e;
            }
            c = et / den;
        }
#pragma unroll
        for (int o = 0; o < 16; ++o)
            acc[o] = fmaf(c, (float)uh_s[o * 1024 + p], acc[o]);
    }
    int lane = t & 63, wid = t >> 6;
#pragma unroll
    for (int o = 0; o < 16; ++o) {
        float v = acc[o];
#pragma unroll
        for (int off = 32; off >= 1; off >>= 1) v += __shfl_xor(v, off, 64);
        if (lane == 0) sred[wid][o] = v;
    }
    __syncthreads();
    if (t < 16) {
        float s = (sred[0][t] + sred[1][t]) + (sred[2][t] + sred[3][t]);
        float n2 = s * s;
#pragma unroll
        for (int off = 1; off < 16; off <<= 1) n2 += __shfl_xor(n2, off, 16);
        float scale = (n2 / (1.f + n2)) / sqrtf(n2 + EPSF);
        vs[t] = s * scale;
        if (last && t == 0) {
            float sv2 = n2 * scale * scale;
            out[b * 10 + tt] = sqrtf(sv2 + EPSF);
        }
    }
    __syncthreads();

    // ---- b-phase: read own slice of blR, write own slice of blW
    if (dob) {
        const float* blr = blR + (b * 10 + tt) * 1024;
        float* blw = blW + (b * 10 + tt) * 1024;
        for (int p = t; p < 1024; p += 256) {
            float d = 0.f;
#pragma unroll
            for (int o = 0; o < 16; ++o) d = fmaf((float)uh_s[o * 1024 + p], vs[o], d);
            blw[p] = first ? d : (blr[p] + d);
        }
    }
}

// ---------------------------------------------------------------------------
extern "C" void kernel_launch(void* const* d_in, const int* in_sizes, int n_in,
                              void* d_out, int out_size, void* d_ws, size_t ws_size,
                              hipStream_t stream) {
    const float* x  = (const float*)d_in[0];
    const float* w1 = (const float*)d_in[1];
    const float* b1 = (const float*)d_in[2];
    const float* w2 = (const float*)d_in[3];
    const float* b2 = (const float*)d_in[4];
    const float* wc = (const float*)d_in[5];
    const float* bc = (const float*)d_in[6];
    const float* Wr = (const float*)d_in[7];
    float* out = (float*)d_out;
    float* ws  = (float*)d_ws;

    // workspace layout (float offsets)
    __bf16* w2a = (__bf16*)(ws);                  // 204800 bf16
    __bf16* wca = (__bf16*)(ws + 102400);         // 524288 bf16
    __bf16* w1b = (__bf16*)(ws + 364544);         // 12288 bf16
    __bf16* h1n = (__bf16*)(ws + 375040);         // 14450688 bf16
    __bf16* h2n = (__bf16*)(ws + 7600384);        // 5914624 bf16
    __bf16* ub  = (__bf16*)(ws + 12654848);       // 2097152 bf16
    float*  blA = ws + 14752000;                  // 655360 f
    __bf16* wrb = (__bf16*)(ws + 15417600);       // 5242880 bf16
    float*  p01 = ws + 18039040;                  // 2 x 5914624 f32 partials
    float*  blB = ws + 29868288;                  // 655360 f (ping-pong)
    __bf16* uhT = (__bf16*)(ws + 375040);         // overlays h1n (dead by k_uhat)

    k_t_w1b<<<48, 256, 0, stream>>>(w1, w1b);
    k_t_w2a<<<800, 256, 0, stream>>>(w2, w2a);
    k_t_wca<<<2048, 256, 0, stream>>>(wc, wca);
    k_t_wrb<<<20480, 256, 0, stream>>>(Wr, wrb);
    k_conv1_mfma<<<dim3(42, 2, 64), 256, 0, stream>>>(x, w1b, b1, h1n);
    k_conv2<<<dim3(8, 64, 2), 192, 0, stream>>>(h1n, w2a, p01);
    k_reduce_h2<<<5776, 256, 0, stream>>>(p01, b2, h2n);
    k_convcaps<<<dim3(8, 64), 256, 0, stream>>>(h2n, wca, bc, ub);
    k_uhat<<<dim3(16, 10, 4), 256, 0, stream>>>(ub, wrb, uhT);
    k_route<<<dim3(64, 10), 256, 0, stream>>>(uhT, blA, blA, out, 1, 1, 0);
    k_route<<<dim3(64, 10), 256, 0, stream>>>(uhT, blA, blB, out, 0, 1, 0);
    k_route<<<dim3(64, 10), 256, 0, stream>>>(uhT, blB, blB, out, 0, 0, 1);
}

// Round 9
// 314.832 us; speedup vs baseline: 1.0929x; 1.0012x over previous
//
#include <hip/hip_runtime.h>
#include <hip/hip_bf16.h>
#include <math.h>

// ---------------------------------------------------------------------------
// GuoCapSAREncoder round 22: conv2 4 waves/block (256 thr), SAME r13/r17
// per-wave inner loop (nt=2, 4 MFMA / 2 A-loads), same 51.4KB LDS, same
// (8,64,2) grid, one stage-phase. Waves/CU 9 -> 12 to hide the ~200cyc L2
// A-load latency that r21 counters show is unhidden (per-block time ~7x
// ideal pipeline; MfmaUtil 22%). Cost: 8x32 tile slots for 190 positions
// (+33% MFMA, absorbed by idle pipe). Staging unchanged (12 slots/thread).
// Routing fusion (r21 ping-pong) and all other kernels frozen.
// ---------------------------------------------------------------------------

#define EPSF 1e-8f

typedef __bf16 bf16x8 __attribute__((ext_vector_type(8)));
typedef __bf16 bf16x4 __attribute__((ext_vector_type(4)));
typedef float floatx4 __attribute__((ext_vector_type(4)));
typedef float floatx16 __attribute__((ext_vector_type(16)));

// ---- weight transposes ----------------------------------------------------
__global__ __launch_bounds__(256) void k_t_w1b(const float* __restrict__ w1, __bf16* __restrict__ w1b) {
    int i = blockIdx.x * 256 + threadIdx.x;          // 12*128*8 = 12288
    if (i >= 12288) return;
    int kt = i >> 10, oc = (i >> 3) & 127, j = i & 7;
    int k = kt * 8 + j;
    w1b[i] = (__bf16)(k < 81 ? w1[oc * 81 + k] : 0.f);
}

// w2[oc64][ic128][khw25] -> w2a frag-ready: f = ((icc*25+khw)*4+ks)*2+mt,
// element [f][lane=h*32+c32][j] = w2[mt*32+c32][icc*64+ks*16+h*8+j][khw]
__global__ __launch_bounds__(256) void k_t_w2a(const float* __restrict__ w2, __bf16* __restrict__ w2a) {
    int i = blockIdx.x * 256 + threadIdx.x;          // 204800
    if (i >= 204800) return;
    int j = i & 7, lane = (i >> 3) & 63, f = i >> 9;
    int mt = f & 1, ks = (f >> 1) & 3, rem = f >> 3;
    int khw = rem % 25, icc = rem / 25;
    int c32 = lane & 31, h = lane >> 5;
    int oc = mt * 32 + c32;
    int ic = icc * 64 + ks * 16 + h * 8 + j;
    w2a[i] = (__bf16)w2[(oc * 128 + ic) * 25 + khw];
}

// wc[oc128][ic64][khw64] -> wca frag-ready: f = (((icc*64+khw)*2+ks)*4+ct,
// element [f][lane][j] = wc[ct*32+c32][icc*32+ks*16+h*8+j][khw]
__global__ __launch_bounds__(256) void k_t_wca(const float* __restrict__ wc, __bf16* __restrict__ wca) {
    int i = blockIdx.x * 256 + threadIdx.x;          // 524288
    if (i >= 524288) return;
    int j = i & 7, lane = (i >> 3) & 63, f = i >> 9;
    int ct = f & 3, ks = (f >> 2) & 1, khw = (f >> 3) & 63, icc = f >> 9;
    int c32 = lane & 31, h = lane >> 5;
    int oc = ct * 32 + c32;
    int ic = icc * 32 + ks * 16 + h * 8 + j;
    wca[i] = (__bf16)wc[(oc * 64 + ic) * 64 + khw];
}

__global__ __launch_bounds__(256) void k_t_wrb(const float* __restrict__ Wr, __bf16* __restrict__ wrb) {
    int i = blockIdx.x * 256 + threadIdx.x;          // 5242880
    if (i >= 5242880) return;
    wrb[i] = (__bf16)Wr[i];
}

// ---- conv1 9x9 + ReLU + maxpool2 via MFMA -> h1n NHWC bf16 [b][42][42][128]
__global__ __launch_bounds__(256, 3) void k_conv1_mfma(const float* __restrict__ x,
                                                       const __bf16* __restrict__ w1b,
                                                       const float* __restrict__ b1,
                                                       __bf16* __restrict__ h1n) {
    __shared__ float xs[960];                        // 10 rows x 92 fp32 (+pad)
    __shared__ __bf16 Bl[18432];                     // 12kt x 2row x 96pos x 8j
    int py = blockIdx.x, ocg = blockIdx.y, b = blockIdx.z;
    int t = threadIdx.x;
    int lane = t & 63, w = t >> 6;
    int cc = lane & 15, q = lane >> 4;

    const float* xb = x + (size_t)b * 8464 + 2 * py * 92;
    for (int j = t; j < 920; j += 256) xs[j] = xb[j];

    int ocA = ocg * 64 + w * 16 + cc;
    bf16x8 af[3];
#pragma unroll
    for (int ks = 0; ks < 3; ++ks)
        af[ks] = *(const bf16x8*)(w1b + ((ks * 4 + q) * 128 + ocA) * 8);

    __syncthreads();

    if (t < 192) {
        int row = t / 96, pos = t - (t / 96) * 96;
        int sbase = row * 92 + pos;
        bool pvalid = pos < 84;
#pragma unroll
        for (int kt = 0; kt < 12; ++kt) {
            bf16x8 pk;
#pragma unroll
            for (int j = 0; j < 8; ++j) {
                int k = kt * 8 + j;
                int kh = k / 9, kw = k - kh * 9;
                float v = (pvalid && k < 81) ? xs[sbase + kh * 92 + kw] : 0.f;
                pk[j] = (__bf16)v;
            }
            *(bf16x8*)(Bl + ((kt * 2 + row) * 96 + pos) * 8) = pk;
        }
    }
    __syncthreads();

    floatx4 acc[2][6];
    const char* Bb = (const char*)Bl + cc * 16 + q * 3072;
#pragma unroll
    for (int rr = 0; rr < 2; ++rr)
#pragma unroll
        for (int n6 = 0; n6 < 6; ++n6) {
            floatx4 a = (floatx4){0.f, 0.f, 0.f, 0.f};
#pragma unroll
            for (int ks = 0; ks < 3; ++ks) {
                bf16x8 bf = *(const bf16x8*)(Bb + ks * 12288 + rr * 1536 + n6 * 256);
                a = __builtin_amdgcn_mfma_f32_16x16x32_bf16(af[ks], bf, a, 0, 0, 0);
            }
            acc[rr][n6] = a;
        }

    int oc0 = ocg * 64 + w * 16 + q * 4;
    float4 bv = *(const float4*)(b1 + oc0);
    size_t obase = (((size_t)b * 42 + py) * 42) * 128 + oc0;
#pragma unroll
    for (int n6 = 0; n6 < 6; ++n6) {
        bf16x4 pk;
#pragma unroll
        for (int r = 0; r < 4; ++r) {
            float vert = fmaxf(acc[0][n6][r], acc[1][n6][r]);
            float hz = fmaxf(vert, __shfl_xor(vert, 1, 64));
            float pooled = fmaxf(hz + ((const float*)&bv)[r], 0.f);
            pk[r] = (__bf16)pooled;
        }
        if ((cc & 1) == 0) {
            int px = n6 * 8 + (cc >> 1);
            if (px < 42)
                *(bf16x4*)(h1n + obase + (size_t)px * 128) = pk;
        }
    }
}

// ---- conv2 5x5 via MFMA 32x32x16, icc-split, 4 waves/block ----------------
// grid (8, 64, 2); 256 thr = 4 waves x nt=2 -> 8 position tiles (190 valid).
// Writes fp32 partials to p01 + icc*5914624, layout [b][38][38][64] f32.
__global__ __launch_bounds__(256, 2) void k_conv2(const __bf16* __restrict__ h1n,
                                                  const __bf16* __restrict__ w2a,
                                                  float* __restrict__ p01) {
    __shared__ __bf16 ins[25704];                    // 378 pos * 136 B = 51408 B
    int g = blockIdx.x, b = blockIdx.y, icc = blockIdx.z;
    int row0 = g * 5;
    int t = threadIdx.x;
    int lane = t & 63, w = t >> 6;                   // w in [0,4)
    int c32 = lane & 31, h = lane >> 5;
    int validp = (g < 7) ? 190 : 114;
    int ic0 = icc * 64;

    int baseN[2], posi[2];
#pragma unroll
    for (int nt = 0; nt < 2; ++nt) {
        int pi = (w * 2 + nt) * 32 + c32;            // 8 tiles x 32 = 256 slots
        int pc = pi < validp ? pi : validp - 1;
        int r = pc / 38, c = pc - r * 38;
        posi[nt] = pi;
        baseN[nt] = (r * 42 + c) * 136 + h * 16;
    }

    // batched staging: 12 fixed slots per thread (3024 total, tail clamped)
#pragma unroll
    for (int half = 0; half < 2; ++half) {
        uint4 rb[6];
        int lo[6];
#pragma unroll
        for (int k = 0; k < 6; ++k) {
            int j = (half * 6 + k) * 256 + t;
            if (j > 3023) j -= 256;                  // only half=1,k=5,t>=208
            int lr = j / 336, rem = j - lr * 336;
            int ix = rem >> 3, sb = rem & 7;
            int rg = row0 + lr; if (rg > 41) rg = 41;
            rb[k] = *(const uint4*)(h1n + ((((size_t)b * 42 + rg) * 42 + ix) * 128 + ic0 + sb * 8));
            lo[k] = (lr * 42 + ix) * 136 + sb * 16;
        }
#pragma unroll
        for (int k = 0; k < 6; ++k)
            *(uint4*)((char*)ins + lo[k]) = rb[k];
    }

    floatx16 acc[2][2];
#pragma unroll
    for (int mt = 0; mt < 2; ++mt)
#pragma unroll
        for (int nt = 0; nt < 2; ++nt)
#pragma unroll
            for (int i = 0; i < 16; ++i) acc[mt][nt][i] = 0.f;

    __syncthreads();
    const __bf16* wic = w2a + (size_t)icc * 25 * 4096 + (lane << 3);
#pragma unroll
    for (int khw = 0; khw < 25; ++khw) {
        int kh = khw / 5, kw = khw - kh * 5;
        int doff = (kh * 42 + kw) * 136;
        const __bf16* wk = wic + khw * 4096;         // 4 ks x 2 mt x 512
#pragma unroll
        for (int ks = 0; ks < 4; ++ks) {
            bf16x8 a0 = *(const bf16x8*)(wk + ks * 1024);
            bf16x8 a1 = *(const bf16x8*)(wk + ks * 1024 + 512);
#pragma unroll
            for (int nt = 0; nt < 2; ++nt) {
                bf16x8 bfr = *(const bf16x8*)((char*)ins + baseN[nt] + doff + ks * 32);
                acc[0][nt] = __builtin_amdgcn_mfma_f32_32x32x16_bf16(a0, bfr, acc[0][nt], 0, 0, 0);
                acc[1][nt] = __builtin_amdgcn_mfma_f32_32x32x16_bf16(a1, bfr, acc[1][nt], 0, 0, 0);
            }
        }
    }
    float* pdst = p01 + (size_t)icc * 5914624;
#pragma unroll
    for (int nt = 0; nt < 2; ++nt) {
        int pi = posi[nt];
        if (pi < validp) {
            int r = pi / 38, c = pi - r * 38;
            int oh = row0 + r;
            size_t obase = (((size_t)b * 38 + oh) * 38 + c) * 64;
#pragma unroll
            for (int mt = 0; mt < 2; ++mt) {
#pragma unroll
                for (int g2 = 0; g2 < 4; ++g2) {
                    int oc0 = mt * 32 + g2 * 8 + h * 4;
                    floatx4 pv;
                    pv[0] = acc[mt][nt][g2 * 4 + 0];
                    pv[1] = acc[mt][nt][g2 * 4 + 1];
                    pv[2] = acc[mt][nt][g2 * 4 + 2];
                    pv[3] = acc[mt][nt][g2 * 4 + 3];
                    *(floatx4*)(pdst + obase + oc0) = pv;
                }
            }
        }
    }
}

// ---- reduce: h2n = bf16(p0 + p1 + b2) -- pure streaming, HBM-rate ---------
__global__ __launch_bounds__(256) void k_reduce_h2(const float* __restrict__ p01,
                                                   const float* __restrict__ b2,
                                                   __bf16* __restrict__ h2n) {
    int i = blockIdx.x * 256 + threadIdx.x;          // 1478656 groups of 4
    if (i >= 1478656) return;
    size_t e = (size_t)i * 4;
    floatx4 a = *(const floatx4*)(p01 + e);
    floatx4 b = *(const floatx4*)(p01 + 5914624 + e);
    floatx4 bv = *(const floatx4*)(b2 + ((i * 4) & 63));
    bf16x4 pk;
    pk.x = (__bf16)(a[0] + b[0] + bv[0]);
    pk.y = (__bf16)(a[1] + b[1] + bv[1]);
    pk.z = (__bf16)(a[2] + b[2] + bv[2]);
    pk.w = (__bf16)(a[3] + b[3] + bv[3]);
    *(bf16x4*)(h2n + e) = pk;
}

// ---- caps conv 8x8 s2 via MFMA 32x32x16 + FUSED squash -> ub bf16 ---------
// Staging batched (6 fixed slots per thread, load-all-then-write-all).
__global__ __launch_bounds__(256, 4) void k_convcaps(const __bf16* __restrict__ h2n,
                                                     const __bf16* __restrict__ wca,
                                                     const float* __restrict__ bc,
                                                     __bf16* __restrict__ ub) {
    __shared__ __bf16 ins[13680];                    // 380 * 72 B = 27360 B
    int g = blockIdx.x, b = blockIdx.y;              // g in [0,8)
    int t = threadIdx.x;
    int lane = t & 63, ct = t >> 6;                  // wave = capsule type
    int c32 = lane & 31, h = lane >> 5;
    int rloc = c32 >> 4, cx = c32 & 15;

    floatx16 acc;
#pragma unroll
    for (int i = 0; i < 16; ++i) acc[i] = 0.f;

    int Bbase = (76 * rloc + cx) * 72 + h * 16;      // lane byte base in slab
    for (int icc = 0; icc < 2; ++icc) {
        int ic0 = icc * 32;
        __syncthreads();
        {
            uint4 rb[6];
            int lo[6];
#pragma unroll
            for (int k = 0; k < 6; ++k) {
                int j = k * 256 + t;
                if (j > 1519) j -= 256;              // only k=5, t>=240
                int r = j / 152, rem = j - r * 152;
                int c = rem >> 2, s = rem & 3;
                rb[k] = *(const uint4*)(h2n + ((((size_t)b * 38 + 4 * g + r) * 38 + c) * 64 + ic0 + s * 8));
                int X = (r * 2 + (c & 1)) * 19 + (c >> 1);
                lo[k] = X * 72 + s * 16;
            }
#pragma unroll
            for (int k = 0; k < 6; ++k)
                *(uint4*)((char*)ins + lo[k]) = rb[k];
        }
        __syncthreads();
        const __bf16* wic = wca + ((size_t)icc * 64 * 8 + ct) * 512 + (lane << 3);
#pragma unroll
        for (int khw = 0; khw < 64; ++khw) {
            int kh = khw >> 3, kw = khw & 7;
            int par = kw & 1, k2 = kw >> 1;
            int doff = ((kh * 2 + par) * 19 + k2) * 72;
            const __bf16* wk = wic + khw * 4096;     // 2 ks x 4 ct x 512
#pragma unroll
            for (int ks = 0; ks < 2; ++ks) {
                bf16x8 af = *(const bf16x8*)(wk + ks * 2048);
                bf16x8 bfr = *(const bf16x8*)((char*)ins + Bbase + doff + ks * 32);
                acc = __builtin_amdgcn_mfma_f32_32x32x16_bf16(af, bfr, acc, 0, 0, 0);
            }
        }
    }
    // fused bias + squash
    float vals[16];
    float n2p = 0.f;
#pragma unroll
    for (int g2 = 0; g2 < 4; ++g2) {
        float4 bv = *(const float4*)(bc + ct * 32 + g2 * 8 + h * 4);
#pragma unroll
        for (int j = 0; j < 4; ++j) {
            float v = acc[g2 * 4 + j] + ((const float*)&bv)[j];
            vals[g2 * 4 + j] = v;
            n2p = fmaf(v, v, n2p);
        }
    }
    float n2 = n2p + __shfl_xor(n2p, 32, 64);
    float scale = (n2 / (1.f + n2)) / sqrtf(n2 + EPSF);
    int pos = (2 * g + rloc) * 16 + cx;              // y*16 + x
    __bf16* dst = ub + (((size_t)b * 1024 + ct * 256 + pos) * 32);
#pragma unroll
    for (int g2 = 0; g2 < 4; ++g2) {
        bf16x4 pk;
        pk.x = (__bf16)(vals[g2 * 4 + 0] * scale);
        pk.y = (__bf16)(vals[g2 * 4 + 1] * scale);
        pk.z = (__bf16)(vals[g2 * 4 + 2] * scale);
        pk.w = (__bf16)(vals[g2 * 4 + 3] * scale);
        *(bf16x4*)(dst + g2 * 8 + h * 4) = pk;
    }
}

// ---- u_hat: ub bf16 [64,1024,32] x wrb bf16 [1024,10,16,32] -> uhT bf16 ---
__global__ __launch_bounds__(256, 2) void k_uhat(const __bf16* __restrict__ ub,
                                                 const __bf16* __restrict__ wrb,
                                                 __bf16* __restrict__ uhT) {
    int pt = blockIdx.x, ts = blockIdx.y, bz = blockIdx.z;
    int t = threadIdx.x;
    int p = pt * 64 + (t & 63);
    int q = t >> 6;
    bf16x8 wf[4][4];
#pragma unroll
    for (int o4 = 0; o4 < 4; ++o4)
#pragma unroll
        for (int j = 0; j < 4; ++j)
            wf[o4][j] = *(const bf16x8*)(wrb + (((size_t)p * 10 + ts) * 16 + q * 4 + o4) * 32 + j * 8);
#pragma unroll 1
    for (int bi = 0; bi < 16; ++bi) {
        int b = bz * 16 + bi;
        bf16x8 uf[4];
        const bf16x8* up = (const bf16x8*)(ub + ((size_t)b * 1024 + p) * 32);
#pragma unroll
        for (int j = 0; j < 4; ++j) uf[j] = up[j];
#pragma unroll
        for (int o4 = 0; o4 < 4; ++o4) {
            float s = 0.f;
#pragma unroll
            for (int j = 0; j < 4; ++j)
#pragma unroll
                for (int e = 0; e < 8; ++e)
                    s = fmaf((float)uf[j][e], (float)wf[o4][j][e], s);
            uhT[(((size_t)b * 10 + ts) * 16 + q * 4 + o4) * 1024 + p] = (__bf16)s;
        }
    }
}

// ---- fused routing step with bl ping-pong ---------------------------------
__global__ __launch_bounds__(256) void k_route(const __bf16* __restrict__ uhT,
                                               const float* __restrict__ blR,
                                               float* __restrict__ blW,
                                               float* __restrict__ out,
                                               int first, int dob, int last) {
    __shared__ __bf16 uh_s[16384];                   // 32 KB: [o][p]
    __shared__ float sred[4][16];
    __shared__ float vs[16];
    int b = blockIdx.x, tt = blockIdx.y;
    int t = threadIdx.x;
    const __bf16* uhb = uhT + ((size_t)b * 10 + tt) * 16384;
#pragma unroll
    for (int k = 0; k < 8; ++k) {
        int j = k * 256 + t;
        *(uint4*)((char*)uh_s + j * 16) = *(const uint4*)((const char*)uhb + j * 16);
    }
    __syncthreads();

    // ---- s-phase
    float acc[16];
#pragma unroll
    for (int o = 0; o < 16; ++o) acc[o] = 0.f;
    const float* blb = blR + b * 10240;
    for (int p = t; p < 1024; p += 256) {
        float c;
        if (first) {
            c = 0.1f;
        } else {
            float den = 0.f, et = 0.f;
#pragma unroll
            for (int tp = 0; tp < 10; ++tp) {
                float e = expf(blb[tp * 1024 + p]);
                den += e;
                if (tp == tt) et = e;
            }
            c = et / den;
        }
#pragma unroll
        for (int o = 0; o < 16; ++o)
            acc[o] = fmaf(c, (float)uh_s[o * 1024 + p], acc[o]);
    }
    int lane = t & 63, wid = t >> 6;
#pragma unroll
    for (int o = 0; o < 16; ++o) {
        float v = acc[o];
#pragma unroll
        for (int off = 32; off >= 1; off >>= 1) v += __shfl_xor(v, off, 64);
        if (lane == 0) sred[wid][o] = v;
    }
    __syncthreads();
    if (t < 16) {
        float s = (sred[0][t] + sred[1][t]) + (sred[2][t] + sred[3][t]);
        float n2 = s * s;
#pragma unroll
        for (int off = 1; off < 16; off <<= 1) n2 += __shfl_xor(n2, off, 16);
        float scale = (n2 / (1.f + n2)) / sqrtf(n2 + EPSF);
        vs[t] = s * scale;
        if (last && t == 0) {
            float sv2 = n2 * scale * scale;
            out[b * 10 + tt] = sqrtf(sv2 + EPSF);
        }
    }
    __syncthreads();

    // ---- b-phase: read own slice of blR, write own slice of blW
    if (dob) {
        const float* blr = blR + (b * 10 + tt) * 1024;
        float* blw = blW + (b * 10 + tt) * 1024;
        for (int p = t; p < 1024; p += 256) {
            float d = 0.f;
#pragma unroll
            for (int o = 0; o < 16; ++o) d = fmaf((float)uh_s[o * 1024 + p], vs[o], d);
            blw[p] = first ? d : (blr[p] + d);
        }
    }
}

// ---------------------------------------------------------------------------
extern "C" void kernel_launch(void* const* d_in, const int* in_sizes, int n_in,
                              void* d_out, int out_size, void* d_ws, size_t ws_size,
                              hipStream_t stream) {
    const float* x  = (const float*)d_in[0];
    const float* w1 = (const float*)d_in[1];
    const float* b1 = (const float*)d_in[2];
    const float* w2 = (const float*)d_in[3];
    const float* b2 = (const float*)d_in[4];
    const float* wc = (const float*)d_in[5];
    const float* bc = (const float*)d_in[6];
    const float* Wr = (const float*)d_in[7];
    float* out = (float*)d_out;
    float* ws  = (float*)d_ws;

    // workspace layout (float offsets)
    __bf16* w2a = (__bf16*)(ws);                  // 204800 bf16
    __bf16* wca = (__bf16*)(ws + 102400);         // 524288 bf16
    __bf16* w1b = (__bf16*)(ws + 364544);         // 12288 bf16
    __bf16* h1n = (__bf16*)(ws + 375040);         // 14450688 bf16
    __bf16* h2n = (__bf16*)(ws + 7600384);        // 5914624 bf16
    __bf16* ub  = (__bf16*)(ws + 12654848);       // 2097152 bf16
    float*  blA = ws + 14752000;                  // 655360 f
    __bf16* wrb = (__bf16*)(ws + 15417600);       // 5242880 bf16
    float*  p01 = ws + 18039040;                  // 2 x 5914624 f32 partials
    float*  blB = ws + 29868288;                  // 655360 f (ping-pong)
    __bf16* uhT = (__bf16*)(ws + 375040);         // overlays h1n (dead by k_uhat)

    k_t_w1b<<<48, 256, 0, stream>>>(w1, w1b);
    k_t_w2a<<<800, 256, 0, stream>>>(w2, w2a);
    k_t_wca<<<2048, 256, 0, stream>>>(wc, wca);
    k_t_wrb<<<20480, 256, 0, stream>>>(Wr, wrb);
    k_conv1_mfma<<<dim3(42, 2, 64), 256, 0, stream>>>(x, w1b, b1, h1n);
    k_conv2<<<dim3(8, 64, 2), 256, 0, stream>>>(h1n, w2a, p01);
    k_reduce_h2<<<5776, 256, 0, stream>>>(p01, b2, h2n);
    k_convcaps<<<dim3(8, 64), 256, 0, stream>>>(h2n, wca, bc, ub);
    k_uhat<<<dim3(16, 10, 4), 256, 0, stream>>>(ub, wrb, uhT);
    k_route<<<dim3(64, 10), 256, 0, stream>>>(uhT, blA, blA, out, 1, 1, 0);
    k_route<<<dim3(64, 10), 256, 0, stream>>>(uhT, blA, blB, out, 0, 1, 0);
    k_route<<<dim3(64, 10), 256, 0, stream>>>(uhT, blB, blB, out, 0, 0, 1);
}

// Round 10
// 307.140 us; speedup vs baseline: 1.1203x; 1.0250x over previous
//
#include <hip/hip_runtime.h>
#include <hip/hip_bf16.h>
#include <math.h>

// ---------------------------------------------------------------------------
// GuoCapSAREncoder round 23:
// (1) conv2 A-load SOFTWARE PIPELINE. r13-r22 ladder: every occupancy knob
//     leaves conv2 at ~70-72us; VGPR=68 shows the compiler keeps almost no
//     A-loads in flight -> 200 L2 loads/wave run ~serially (200x200cyc x2
//     rounds ~= measured 86K cyc). Fix: 3-buffer rotation abuf[3][8] (static
//     idx under full unroll) issuing khw+2's 8 loads before computing khw;
//     launch_bounds(256) w/o min-wave cap frees VGPRs for the buffers.
// (2) 4 transpose kernels merged into 1 (launch overhead, 12->9 dispatches).
// Everything else frozen from r22 (314.8us best).
// ---------------------------------------------------------------------------

#define EPSF 1e-8f

typedef __bf16 bf16x8 __attribute__((ext_vector_type(8)));
typedef __bf16 bf16x4 __attribute__((ext_vector_type(4)));
typedef float floatx4 __attribute__((ext_vector_type(4)));
typedef float floatx16 __attribute__((ext_vector_type(16)));

// ---- merged weight transposes ---------------------------------------------
// [0, 5242880)              : wrb[i]  = Wr[i]
// [5242880, +524288)        : wca frag-ready
// [.., +204800)             : w2a frag-ready
// [.., +12288)              : w1b
__global__ __launch_bounds__(256) void k_t_all(const float* __restrict__ Wr,
                                               const float* __restrict__ wc,
                                               const float* __restrict__ w2,
                                               const float* __restrict__ w1,
                                               __bf16* __restrict__ wrb,
                                               __bf16* __restrict__ wca,
                                               __bf16* __restrict__ w2a,
                                               __bf16* __restrict__ w1b) {
    int i = blockIdx.x * 256 + threadIdx.x;
    if (i < 5242880) {
        wrb[i] = (__bf16)Wr[i];
        return;
    }
    int i2 = i - 5242880;
    if (i2 < 524288) {
        int j = i2 & 7, lane = (i2 >> 3) & 63, f = i2 >> 9;
        int ct = f & 3, ks = (f >> 2) & 1, khw = (f >> 3) & 63, icc = f >> 9;
        int c32 = lane & 31, h = lane >> 5;
        int oc = ct * 32 + c32;
        int ic = icc * 32 + ks * 16 + h * 8 + j;
        wca[i2] = (__bf16)wc[(oc * 64 + ic) * 64 + khw];
        return;
    }
    int i3 = i2 - 524288;
    if (i3 < 204800) {
        int j = i3 & 7, lane = (i3 >> 3) & 63, f = i3 >> 9;
        int mt = f & 1, ks = (f >> 1) & 3, rem = f >> 3;
        int khw = rem % 25, icc = rem / 25;
        int c32 = lane & 31, h = lane >> 5;
        int oc = mt * 32 + c32;
        int ic = icc * 64 + ks * 16 + h * 8 + j;
        w2a[i3] = (__bf16)w2[(oc * 128 + ic) * 25 + khw];
        return;
    }
    int i4 = i3 - 204800;
    if (i4 < 12288) {
        int kt = i4 >> 10, oc = (i4 >> 3) & 127, j = i4 & 7;
        int k = kt * 8 + j;
        w1b[i4] = (__bf16)(k < 81 ? w1[oc * 81 + k] : 0.f);
    }
}

// ---- conv1 9x9 + ReLU + maxpool2 via MFMA -> h1n NHWC bf16 [b][42][42][128]
__global__ __launch_bounds__(256, 3) void k_conv1_mfma(const float* __restrict__ x,
                                                       const __bf16* __restrict__ w1b,
                                                       const float* __restrict__ b1,
                                                       __bf16* __restrict__ h1n) {
    __shared__ float xs[960];                        // 10 rows x 92 fp32 (+pad)
    __shared__ __bf16 Bl[18432];                     // 12kt x 2row x 96pos x 8j
    int py = blockIdx.x, ocg = blockIdx.y, b = blockIdx.z;
    int t = threadIdx.x;
    int lane = t & 63, w = t >> 6;
    int cc = lane & 15, q = lane >> 4;

    const float* xb = x + (size_t)b * 8464 + 2 * py * 92;
    for (int j = t; j < 920; j += 256) xs[j] = xb[j];

    int ocA = ocg * 64 + w * 16 + cc;
    bf16x8 af[3];
#pragma unroll
    for (int ks = 0; ks < 3; ++ks)
        af[ks] = *(const bf16x8*)(w1b + ((ks * 4 + q) * 128 + ocA) * 8);

    __syncthreads();

    if (t < 192) {
        int row = t / 96, pos = t - (t / 96) * 96;
        int sbase = row * 92 + pos;
        bool pvalid = pos < 84;
#pragma unroll
        for (int kt = 0; kt < 12; ++kt) {
            bf16x8 pk;
#pragma unroll
            for (int j = 0; j < 8; ++j) {
                int k = kt * 8 + j;
                int kh = k / 9, kw = k - kh * 9;
                float v = (pvalid && k < 81) ? xs[sbase + kh * 92 + kw] : 0.f;
                pk[j] = (__bf16)v;
            }
            *(bf16x8*)(Bl + ((kt * 2 + row) * 96 + pos) * 8) = pk;
        }
    }
    __syncthreads();

    floatx4 acc[2][6];
    const char* Bb = (const char*)Bl + cc * 16 + q * 3072;
#pragma unroll
    for (int rr = 0; rr < 2; ++rr)
#pragma unroll
        for (int n6 = 0; n6 < 6; ++n6) {
            floatx4 a = (floatx4){0.f, 0.f, 0.f, 0.f};
#pragma unroll
            for (int ks = 0; ks < 3; ++ks) {
                bf16x8 bf = *(const bf16x8*)(Bb + ks * 12288 + rr * 1536 + n6 * 256);
                a = __builtin_amdgcn_mfma_f32_16x16x32_bf16(af[ks], bf, a, 0, 0, 0);
            }
            acc[rr][n6] = a;
        }

    int oc0 = ocg * 64 + w * 16 + q * 4;
    float4 bv = *(const float4*)(b1 + oc0);
    size_t obase = (((size_t)b * 42 + py) * 42) * 128 + oc0;
#pragma unroll
    for (int n6 = 0; n6 < 6; ++n6) {
        bf16x4 pk;
#pragma unroll
        for (int r = 0; r < 4; ++r) {
            float vert = fmaxf(acc[0][n6][r], acc[1][n6][r]);
            float hz = fmaxf(vert, __shfl_xor(vert, 1, 64));
            float pooled = fmaxf(hz + ((const float*)&bv)[r], 0.f);
            pk[r] = (__bf16)pooled;
        }
        if ((cc & 1) == 0) {
            int px = n6 * 8 + (cc >> 1);
            if (px < 42)
                *(bf16x4*)(h1n + obase + (size_t)px * 128) = pk;
        }
    }
}

// ---- conv2 5x5 via MFMA 32x32x16, icc-split, A-load pipelined -------------
// grid (8, 64, 2); 256 thr = 4 waves; one stage-phase; 3-buffer A rotation:
// loads for khw+2 issue before compute of khw (depth-2 latency cover).
__global__ __launch_bounds__(256) void k_conv2(const __bf16* __restrict__ h1n,
                                               const __bf16* __restrict__ w2a,
                                               float* __restrict__ p01) {
    __shared__ __bf16 ins[25704];                    // 378 pos * 136 B = 51408 B
    int g = blockIdx.x, b = blockIdx.y, icc = blockIdx.z;
    int row0 = g * 5;
    int t = threadIdx.x;
    int lane = t & 63, w = t >> 6;                   // w in [0,4)
    int c32 = lane & 31, h = lane >> 5;
    int validp = (g < 7) ? 190 : 114;
    int ic0 = icc * 64;

    int baseN[2], posi[2];
#pragma unroll
    for (int nt = 0; nt < 2; ++nt) {
        int pi = (w * 2 + nt) * 32 + c32;            // 8 tiles x 32 = 256 slots
        int pc = pi < validp ? pi : validp - 1;
        int r = pc / 38, c = pc - r * 38;
        posi[nt] = pi;
        baseN[nt] = (r * 42 + c) * 136 + h * 16;
    }

    // batched staging: 12 fixed slots per thread (3024 total, tail clamped)
#pragma unroll
    for (int half = 0; half < 2; ++half) {
        uint4 rb[6];
        int lo[6];
#pragma unroll
        for (int k = 0; k < 6; ++k) {
            int j = (half * 6 + k) * 256 + t;
            if (j > 3023) j -= 256;                  // only half=1,k=5,t>=208
            int lr = j / 336, rem = j - lr * 336;
            int ix = rem >> 3, sb = rem & 7;
            int rg = row0 + lr; if (rg > 41) rg = 41;
            rb[k] = *(const uint4*)(h1n + ((((size_t)b * 42 + rg) * 42 + ix) * 128 + ic0 + sb * 8));
            lo[k] = (lr * 42 + ix) * 136 + sb * 16;
        }
#pragma unroll
        for (int k = 0; k < 6; ++k)
            *(uint4*)((char*)ins + lo[k]) = rb[k];
    }

    floatx16 acc[2][2];
#pragma unroll
    for (int mt = 0; mt < 2; ++mt)
#pragma unroll
        for (int nt = 0; nt < 2; ++nt)
#pragma unroll
            for (int i = 0; i < 16; ++i) acc[mt][nt][i] = 0.f;

    const __bf16* wic = w2a + (size_t)icc * 25 * 4096 + (lane << 3);

    // A-frag pipeline: abuf[p][ks*2+mt], rotation over 3 parities
    bf16x8 abuf[3][8];
#pragma unroll
    for (int ks = 0; ks < 4; ++ks) {
        abuf[0][ks * 2]     = *(const bf16x8*)(wic + 0 * 4096 + ks * 1024);
        abuf[0][ks * 2 + 1] = *(const bf16x8*)(wic + 0 * 4096 + ks * 1024 + 512);
        abuf[1][ks * 2]     = *(const bf16x8*)(wic + 1 * 4096 + ks * 1024);
        abuf[1][ks * 2 + 1] = *(const bf16x8*)(wic + 1 * 4096 + ks * 1024 + 512);
    }

    __syncthreads();
#pragma unroll
    for (int khw = 0; khw < 25; ++khw) {
        // prefetch khw+2 into the buffer freed at khw-1
        if (khw + 2 < 25) {
            const __bf16* wk2 = wic + (khw + 2) * 4096;
#pragma unroll
            for (int ks = 0; ks < 4; ++ks) {
                abuf[(khw + 2) % 3][ks * 2]     = *(const bf16x8*)(wk2 + ks * 1024);
                abuf[(khw + 2) % 3][ks * 2 + 1] = *(const bf16x8*)(wk2 + ks * 1024 + 512);
            }
        }
        int kh = khw / 5, kw = khw - kh * 5;
        int doff = (kh * 42 + kw) * 136;
#pragma unroll
        for (int ks = 0; ks < 4; ++ks) {
            bf16x8 a0 = abuf[khw % 3][ks * 2];
            bf16x8 a1 = abuf[khw % 3][ks * 2 + 1];
#pragma unroll
            for (int nt = 0; nt < 2; ++nt) {
                bf16x8 bfr = *(const bf16x8*)((char*)ins + baseN[nt] + doff + ks * 32);
                acc[0][nt] = __builtin_amdgcn_mfma_f32_32x32x16_bf16(a0, bfr, acc[0][nt], 0, 0, 0);
                acc[1][nt] = __builtin_amdgcn_mfma_f32_32x32x16_bf16(a1, bfr, acc[1][nt], 0, 0, 0);
            }
        }
    }
    float* pdst = p01 + (size_t)icc * 5914624;
#pragma unroll
    for (int nt = 0; nt < 2; ++nt) {
        int pi = posi[nt];
        if (pi < validp) {
            int r = pi / 38, c = pi - r * 38;
            int oh = row0 + r;
            size_t obase = (((size_t)b * 38 + oh) * 38 + c) * 64;
#pragma unroll
            for (int mt = 0; mt < 2; ++mt) {
#pragma unroll
                for (int g2 = 0; g2 < 4; ++g2) {
                    int oc0 = mt * 32 + g2 * 8 + h * 4;
                    floatx4 pv;
                    pv[0] = acc[mt][nt][g2 * 4 + 0];
                    pv[1] = acc[mt][nt][g2 * 4 + 1];
                    pv[2] = acc[mt][nt][g2 * 4 + 2];
                    pv[3] = acc[mt][nt][g2 * 4 + 3];
                    *(floatx4*)(pdst + obase + oc0) = pv;
                }
            }
        }
    }
}

// ---- reduce: h2n = bf16(p0 + p1 + b2) -- pure streaming, HBM-rate ---------
__global__ __launch_bounds__(256) void k_reduce_h2(const float* __restrict__ p01,
                                                   const float* __restrict__ b2,
                                                   __bf16* __restrict__ h2n) {
    int i = blockIdx.x * 256 + threadIdx.x;          // 1478656 groups of 4
    if (i >= 1478656) return;
    size_t e = (size_t)i * 4;
    floatx4 a = *(const floatx4*)(p01 + e);
    floatx4 b = *(const floatx4*)(p01 + 5914624 + e);
    floatx4 bv = *(const floatx4*)(b2 + ((i * 4) & 63));
    bf16x4 pk;
    pk.x = (__bf16)(a[0] + b[0] + bv[0]);
    pk.y = (__bf16)(a[1] + b[1] + bv[1]);
    pk.z = (__bf16)(a[2] + b[2] + bv[2]);
    pk.w = (__bf16)(a[3] + b[3] + bv[3]);
    *(bf16x4*)(h2n + e) = pk;
}

// ---- caps conv 8x8 s2 via MFMA 32x32x16 + FUSED squash -> ub bf16 ---------
__global__ __launch_bounds__(256, 4) void k_convcaps(const __bf16* __restrict__ h2n,
                                                     const __bf16* __restrict__ wca,
                                                     const float* __restrict__ bc,
                                                     __bf16* __restrict__ ub) {
    __shared__ __bf16 ins[13680];                    // 380 * 72 B = 27360 B
    int g = blockIdx.x, b = blockIdx.y;              // g in [0,8)
    int t = threadIdx.x;
    int lane = t & 63, ct = t >> 6;                  // wave = capsule type
    int c32 = lane & 31, h = lane >> 5;
    int rloc = c32 >> 4, cx = c32 & 15;

    floatx16 acc;
#pragma unroll
    for (int i = 0; i < 16; ++i) acc[i] = 0.f;

    int Bbase = (76 * rloc + cx) * 72 + h * 16;      // lane byte base in slab
    for (int icc = 0; icc < 2; ++icc) {
        int ic0 = icc * 32;
        __syncthreads();
        {
            uint4 rb[6];
            int lo[6];
#pragma unroll
            for (int k = 0; k < 6; ++k) {
                int j = k * 256 + t;
                if (j > 1519) j -= 256;              // only k=5, t>=240
                int r = j / 152, rem = j - r * 152;
                int c = rem >> 2, s = rem & 3;
                rb[k] = *(const uint4*)(h2n + ((((size_t)b * 38 + 4 * g + r) * 38 + c) * 64 + ic0 + s * 8));
                int X = (r * 2 + (c & 1)) * 19 + (c >> 1);
                lo[k] = X * 72 + s * 16;
            }
#pragma unroll
            for (int k = 0; k < 6; ++k)
                *(uint4*)((char*)ins + lo[k]) = rb[k];
        }
        __syncthreads();
        const __bf16* wic = wca + ((size_t)icc * 64 * 8 + ct) * 512 + (lane << 3);
#pragma unroll
        for (int khw = 0; khw < 64; ++khw) {
            int kh = khw >> 3, kw = khw & 7;
            int par = kw & 1, k2 = kw >> 1;
            int doff = ((kh * 2 + par) * 19 + k2) * 72;
            const __bf16* wk = wic + khw * 4096;     // 2 ks x 4 ct x 512
#pragma unroll
            for (int ks = 0; ks < 2; ++ks) {
                bf16x8 af = *(const bf16x8*)(wk + ks * 2048);
                bf16x8 bfr = *(const bf16x8*)((char*)ins + Bbase + doff + ks * 32);
                acc = __builtin_amdgcn_mfma_f32_32x32x16_bf16(af, bfr, acc, 0, 0, 0);
            }
        }
    }
    // fused bias + squash
    float vals[16];
    float n2p = 0.f;
#pragma unroll
    for (int g2 = 0; g2 < 4; ++g2) {
        float4 bv = *(const float4*)(bc + ct * 32 + g2 * 8 + h * 4);
#pragma unroll
        for (int j = 0; j < 4; ++j) {
            float v = acc[g2 * 4 + j] + ((const float*)&bv)[j];
            vals[g2 * 4 + j] = v;
            n2p = fmaf(v, v, n2p);
        }
    }
    float n2 = n2p + __shfl_xor(n2p, 32, 64);
    float scale = (n2 / (1.f + n2)) / sqrtf(n2 + EPSF);
    int pos = (2 * g + rloc) * 16 + cx;              // y*16 + x
    __bf16* dst = ub + (((size_t)b * 1024 + ct * 256 + pos) * 32);
#pragma unroll
    for (int g2 = 0; g2 < 4; ++g2) {
        bf16x4 pk;
        pk.x = (__bf16)(vals[g2 * 4 + 0] * scale);
        pk.y = (__bf16)(vals[g2 * 4 + 1] * scale);
        pk.z = (__bf16)(vals[g2 * 4 + 2] * scale);
        pk.w = (__bf16)(vals[g2 * 4 + 3] * scale);
        *(bf16x4*)(dst + g2 * 8 + h * 4) = pk;
    }
}

// ---- u_hat: ub bf16 [64,1024,32] x wrb bf16 [1024,10,16,32] -> uhT bf16 ---
__global__ __launch_bounds__(256, 2) void k_uhat(const __bf16* __restrict__ ub,
                                                 const __bf16* __restrict__ wrb,
                                                 __bf16* __restrict__ uhT) {
    int pt = blockIdx.x, ts = blockIdx.y, bz = blockIdx.z;
    int t = threadIdx.x;
    int p = pt * 64 + (t & 63);
    int q = t >> 6;
    bf16x8 wf[4][4];
#pragma unroll
    for (int o4 = 0; o4 < 4; ++o4)
#pragma unroll
        for (int j = 0; j < 4; ++j)
            wf[o4][j] = *(const bf16x8*)(wrb + (((size_t)p * 10 + ts) * 16 + q * 4 + o4) * 32 + j * 8);
#pragma unroll 1
    for (int bi = 0; bi < 16; ++bi) {
        int b = bz * 16 + bi;
        bf16x8 uf[4];
        const bf16x8* up = (const bf16x8*)(ub + ((size_t)b * 1024 + p) * 32);
#pragma unroll
        for (int j = 0; j < 4; ++j) uf[j] = up[j];
#pragma unroll
        for (int o4 = 0; o4 < 4; ++o4) {
            float s = 0.f;
#pragma unroll
            for (int j = 0; j < 4; ++j)
#pragma unroll
                for (int e = 0; e < 8; ++e)
                    s = fmaf((float)uf[j][e], (float)wf[o4][j][e], s);
            uhT[(((size_t)b * 10 + ts) * 16 + q * 4 + o4) * 1024 + p] = (__bf16)s;
        }
    }
}

// ---- fused routing step with bl ping-pong ---------------------------------
__global__ __launch_bounds__(256) void k_route(const __bf16* __restrict__ uhT,
                                               const float* __restrict__ blR,
                                               float* __restrict__ blW,
                                               float* __restrict__ out,
                                               int first, int dob, int last) {
    __shared__ __bf16 uh_s[16384];                   // 32 KB: [o][p]
    __shared__ float sred[4][16];
    __shared__ float vs[16];
    int b = blockIdx.x, tt = blockIdx.y;
    int t = threadIdx.x;
    const __bf16* uhb = uhT + ((size_t)b * 10 + tt) * 16384;
#pragma unroll
    for (int k = 0; k < 8; ++k) {
        int j = k * 256 + t;
        *(uint4*)((char*)uh_s + j * 16) = *(const uint4*)((const char*)uhb + j * 16);
    }
    __syncthreads();

    // ---- s-phase
    float acc[16];
#pragma unroll
    for (int o = 0; o < 16; ++o) acc[o] = 0.f;
    const float* blb = blR + b * 10240;
    for (int p = t; p < 1024; p += 256) {
        float c;
        if (first) {
            c = 0.1f;
        } else {
            float den = 0.f, et = 0.f;
#pragma unroll
            for (int tp = 0; tp < 10; ++tp) {
                float e = expf(blb[tp * 1024 + p]);
                den += e;
                if (tp == tt) et = e;
            }
            c = et / den;
        }
#pragma unroll
        for (int o = 0; o < 16; ++o)
            acc[o] = fmaf(c, (float)uh_s[o * 1024 + p], acc[o]);
    }
    int lane = t & 63, wid = t >> 6;
#pragma unroll
    for (int o = 0; o < 16; ++o) {
        float v = acc[o];
#pragma unroll
        for (int off = 32; off >= 1; off >>= 1) v += __shfl_xor(v, off, 64);
        if (lane == 0) sred[wid][o] = v;
    }
    __syncthreads();
    if (t < 16) {
        float s = (sred[0][t] + sred[1][t]) + (sred[2][t] + sred[3][t]);
        float n2 = s * s;
#pragma unroll
        for (int off = 1; off < 16; off <<= 1) n2 += __shfl_xor(n2, off, 16);
        float scale = (n2 / (1.f + n2)) / sqrtf(n2 + EPSF);
        vs[t] = s * scale;
        if (last && t == 0) {
            float sv2 = n2 * scale * scale;
            out[b * 10 + tt] = sqrtf(sv2 + EPSF);
        }
    }
    __syncthreads();

    // ---- b-phase: read own slice of blR, write own slice of blW
    if (dob) {
        const float* blr = blR + (b * 10 + tt) * 1024;
        float* blw = blW + (b * 10 + tt) * 1024;
        for (int p = t; p < 1024; p += 256) {
            float d = 0.f;
#pragma unroll
            for (int o = 0; o < 16; ++o) d = fmaf((float)uh_s[o * 1024 + p], vs[o], d);
            blw[p] = first ? d : (blr[p] + d);
        }
    }
}

// ---------------------------------------------------------------------------
extern "C" void kernel_launch(void* const* d_in, const int* in_sizes, int n_in,
                              void* d_out, int out_size, void* d_ws, size_t ws_size,
                              hipStream_t stream) {
    const float* x  = (const float*)d_in[0];
    const float* w1 = (const float*)d_in[1];
    const float* b1 = (const float*)d_in[2];
    const float* w2 = (const float*)d_in[3];
    const float* b2 = (const float*)d_in[4];
    const float* wc = (const float*)d_in[5];
    const float* bc = (const float*)d_in[6];
    const float* Wr = (const float*)d_in[7];
    float* out = (float*)d_out;
    float* ws  = (float*)d_ws;

    // workspace layout (float offsets)
    __bf16* w2a = (__bf16*)(ws);                  // 204800 bf16
    __bf16* wca = (__bf16*)(ws + 102400);         // 524288 bf16
    __bf16* w1b = (__bf16*)(ws + 364544);         // 12288 bf16
    __bf16* h1n = (__bf16*)(ws + 375040);         // 14450688 bf16
    __bf16* h2n = (__bf16*)(ws + 7600384);        // 5914624 bf16
    __bf16* ub  = (__bf16*)(ws + 12654848);       // 2097152 bf16
    float*  blA = ws + 14752000;                  // 655360 f
    __bf16* wrb = (__bf16*)(ws + 15417600);       // 5242880 bf16
    float*  p01 = ws + 18039040;                  // 2 x 5914624 f32 partials
    float*  blB = ws + 29868288;                  // 655360 f (ping-pong)
    __bf16* uhT = (__bf16*)(ws + 375040);         // overlays h1n (dead by k_uhat)

    k_t_all<<<23376, 256, 0, stream>>>(Wr, wc, w2, w1, wrb, wca, w2a, w1b);
    k_conv1_mfma<<<dim3(42, 2, 64), 256, 0, stream>>>(x, w1b, b1, h1n);
    k_conv2<<<dim3(8, 64, 2), 256, 0, stream>>>(h1n, w2a, p01);
    k_reduce_h2<<<5776, 256, 0, stream>>>(p01, b2, h2n);
    k_convcaps<<<dim3(8, 64), 256, 0, stream>>>(h2n, wca, bc, ub);
    k_uhat<<<dim3(16, 10, 4), 256, 0, stream>>>(ub, wrb, uhT);
    k_route<<<dim3(64, 10), 256, 0, stream>>>(uhT, blA, blA, out, 1, 1, 0);
    k_route<<<dim3(64, 10), 256, 0, stream>>>(uhT, blA, blB, out, 0, 1, 0);
    k_route<<<dim3(64, 10), 256, 0, stream>>>(uhT, blB, blB, out, 0, 0, 1);
}

// Round 11
// 289.202 us; speedup vs baseline: 1.1898x; 1.0620x over previous
//
#include <hip/hip_runtime.h>
#include <hip/hip_bf16.h>
#include <math.h>

// ---------------------------------------------------------------------------
// GuoCapSAREncoder round 24: convcaps icc-SPLIT (the conv2-proven fix).
// convcaps was structurally pre-split-conv2: 512 blocks (2/CU, grid-limited),
// 2 stage-phases in an icc loop, latency-bound ~45us. Now grid (8,64,2):
// each block = one 32-channel K-half, ONE stage phase, fp32 partials ->
// pc[icc][b][1024][32] overlaid on p01 (dead after k_reduce_h2; no ws
// growth). k_squash (20MB, ~5us) does ub = squash(pc0+pc1+bc). Same
// accumulation reordering that left conv2's absmax bit-identical.
// conv2 kept at r23 (69.6us; 7 variants all ~70 -> structural plateau;
// resource sum LDS 16 + A-L2 24 + MFMA 21 ~= measured). All else frozen.
// ---------------------------------------------------------------------------

#define EPSF 1e-8f

typedef __bf16 bf16x8 __attribute__((ext_vector_type(8)));
typedef __bf16 bf16x4 __attribute__((ext_vector_type(4)));
typedef float floatx4 __attribute__((ext_vector_type(4)));
typedef float floatx16 __attribute__((ext_vector_type(16)));

// ---- merged weight transposes ---------------------------------------------
__global__ __launch_bounds__(256) void k_t_all(const float* __restrict__ Wr,
                                               const float* __restrict__ wc,
                                               const float* __restrict__ w2,
                                               const float* __restrict__ w1,
                                               __bf16* __restrict__ wrb,
                                               __bf16* __restrict__ wca,
                                               __bf16* __restrict__ w2a,
                                               __bf16* __restrict__ w1b) {
    int i = blockIdx.x * 256 + threadIdx.x;
    if (i < 5242880) {
        wrb[i] = (__bf16)Wr[i];
        return;
    }
    int i2 = i - 5242880;
    if (i2 < 524288) {
        int j = i2 & 7, lane = (i2 >> 3) & 63, f = i2 >> 9;
        int ct = f & 3, ks = (f >> 2) & 1, khw = (f >> 3) & 63, icc = f >> 9;
        int c32 = lane & 31, h = lane >> 5;
        int oc = ct * 32 + c32;
        int ic = icc * 32 + ks * 16 + h * 8 + j;
        wca[i2] = (__bf16)wc[(oc * 64 + ic) * 64 + khw];
        return;
    }
    int i3 = i2 - 524288;
    if (i3 < 204800) {
        int j = i3 & 7, lane = (i3 >> 3) & 63, f = i3 >> 9;
        int mt = f & 1, ks = (f >> 1) & 3, rem = f >> 3;
        int khw = rem % 25, icc = rem / 25;
        int c32 = lane & 31, h = lane >> 5;
        int oc = mt * 32 + c32;
        int ic = icc * 64 + ks * 16 + h * 8 + j;
        w2a[i3] = (__bf16)w2[(oc * 128 + ic) * 25 + khw];
        return;
    }
    int i4 = i3 - 204800;
    if (i4 < 12288) {
        int kt = i4 >> 10, oc = (i4 >> 3) & 127, j = i4 & 7;
        int k = kt * 8 + j;
        w1b[i4] = (__bf16)(k < 81 ? w1[oc * 81 + k] : 0.f);
    }
}

// ---- conv1 9x9 + ReLU + maxpool2 via MFMA -> h1n NHWC bf16 [b][42][42][128]
__global__ __launch_bounds__(256, 3) void k_conv1_mfma(const float* __restrict__ x,
                                                       const __bf16* __restrict__ w1b,
                                                       const float* __restrict__ b1,
                                                       __bf16* __restrict__ h1n) {
    __shared__ float xs[960];                        // 10 rows x 92 fp32 (+pad)
    __shared__ __bf16 Bl[18432];                     // 12kt x 2row x 96pos x 8j
    int py = blockIdx.x, ocg = blockIdx.y, b = blockIdx.z;
    int t = threadIdx.x;
    int lane = t & 63, w = t >> 6;
    int cc = lane & 15, q = lane >> 4;

    const float* xb = x + (size_t)b * 8464 + 2 * py * 92;
    for (int j = t; j < 920; j += 256) xs[j] = xb[j];

    int ocA = ocg * 64 + w * 16 + cc;
    bf16x8 af[3];
#pragma unroll
    for (int ks = 0; ks < 3; ++ks)
        af[ks] = *(const bf16x8*)(w1b + ((ks * 4 + q) * 128 + ocA) * 8);

    __syncthreads();

    if (t < 192) {
        int row = t / 96, pos = t - (t / 96) * 96;
        int sbase = row * 92 + pos;
        bool pvalid = pos < 84;
#pragma unroll
        for (int kt = 0; kt < 12; ++kt) {
            bf16x8 pk;
#pragma unroll
            for (int j = 0; j < 8; ++j) {
                int k = kt * 8 + j;
                int kh = k / 9, kw = k - kh * 9;
                float v = (pvalid && k < 81) ? xs[sbase + kh * 92 + kw] : 0.f;
                pk[j] = (__bf16)v;
            }
            *(bf16x8*)(Bl + ((kt * 2 + row) * 96 + pos) * 8) = pk;
        }
    }
    __syncthreads();

    floatx4 acc[2][6];
    const char* Bb = (const char*)Bl + cc * 16 + q * 3072;
#pragma unroll
    for (int rr = 0; rr < 2; ++rr)
#pragma unroll
        for (int n6 = 0; n6 < 6; ++n6) {
            floatx4 a = (floatx4){0.f, 0.f, 0.f, 0.f};
#pragma unroll
            for (int ks = 0; ks < 3; ++ks) {
                bf16x8 bf = *(const bf16x8*)(Bb + ks * 12288 + rr * 1536 + n6 * 256);
                a = __builtin_amdgcn_mfma_f32_16x16x32_bf16(af[ks], bf, a, 0, 0, 0);
            }
            acc[rr][n6] = a;
        }

    int oc0 = ocg * 64 + w * 16 + q * 4;
    float4 bv = *(const float4*)(b1 + oc0);
    size_t obase = (((size_t)b * 42 + py) * 42) * 128 + oc0;
#pragma unroll
    for (int n6 = 0; n6 < 6; ++n6) {
        bf16x4 pk;
#pragma unroll
        for (int r = 0; r < 4; ++r) {
            float vert = fmaxf(acc[0][n6][r], acc[1][n6][r]);
            float hz = fmaxf(vert, __shfl_xor(vert, 1, 64));
            float pooled = fmaxf(hz + ((const float*)&bv)[r], 0.f);
            pk[r] = (__bf16)pooled;
        }
        if ((cc & 1) == 0) {
            int px = n6 * 8 + (cc >> 1);
            if (px < 42)
                *(bf16x4*)(h1n + obase + (size_t)px * 128) = pk;
        }
    }
}

// ---- conv2 5x5 via MFMA 32x32x16, icc-split, A-load pipelined -------------
__global__ __launch_bounds__(256) void k_conv2(const __bf16* __restrict__ h1n,
                                               const __bf16* __restrict__ w2a,
                                               float* __restrict__ p01) {
    __shared__ __bf16 ins[25704];                    // 378 pos * 136 B = 51408 B
    int g = blockIdx.x, b = blockIdx.y, icc = blockIdx.z;
    int row0 = g * 5;
    int t = threadIdx.x;
    int lane = t & 63, w = t >> 6;                   // w in [0,4)
    int c32 = lane & 31, h = lane >> 5;
    int validp = (g < 7) ? 190 : 114;
    int ic0 = icc * 64;

    int baseN[2], posi[2];
#pragma unroll
    for (int nt = 0; nt < 2; ++nt) {
        int pi = (w * 2 + nt) * 32 + c32;            // 8 tiles x 32 = 256 slots
        int pc = pi < validp ? pi : validp - 1;
        int r = pc / 38, c = pc - r * 38;
        posi[nt] = pi;
        baseN[nt] = (r * 42 + c) * 136 + h * 16;
    }

    // batched staging: 12 fixed slots per thread (3024 total, tail clamped)
#pragma unroll
    for (int half = 0; half < 2; ++half) {
        uint4 rb[6];
        int lo[6];
#pragma unroll
        for (int k = 0; k < 6; ++k) {
            int j = (half * 6 + k) * 256 + t;
            if (j > 3023) j -= 256;                  // only half=1,k=5,t>=208
            int lr = j / 336, rem = j - lr * 336;
            int ix = rem >> 3, sb = rem & 7;
            int rg = row0 + lr; if (rg > 41) rg = 41;
            rb[k] = *(const uint4*)(h1n + ((((size_t)b * 42 + rg) * 42 + ix) * 128 + ic0 + sb * 8));
            lo[k] = (lr * 42 + ix) * 136 + sb * 16;
        }
#pragma unroll
        for (int k = 0; k < 6; ++k)
            *(uint4*)((char*)ins + lo[k]) = rb[k];
    }

    floatx16 acc[2][2];
#pragma unroll
    for (int mt = 0; mt < 2; ++mt)
#pragma unroll
        for (int nt = 0; nt < 2; ++nt)
#pragma unroll
            for (int i = 0; i < 16; ++i) acc[mt][nt][i] = 0.f;

    const __bf16* wic = w2a + (size_t)icc * 25 * 4096 + (lane << 3);

    // A-frag pipeline: abuf[p][ks*2+mt], rotation over 3 parities
    bf16x8 abuf[3][8];
#pragma unroll
    for (int ks = 0; ks < 4; ++ks) {
        abuf[0][ks * 2]     = *(const bf16x8*)(wic + 0 * 4096 + ks * 1024);
        abuf[0][ks * 2 + 1] = *(const bf16x8*)(wic + 0 * 4096 + ks * 1024 + 512);
        abuf[1][ks * 2]     = *(const bf16x8*)(wic + 1 * 4096 + ks * 1024);
        abuf[1][ks * 2 + 1] = *(const bf16x8*)(wic + 1 * 4096 + ks * 1024 + 512);
    }

    __syncthreads();
#pragma unroll
    for (int khw = 0; khw < 25; ++khw) {
        if (khw + 2 < 25) {
            const __bf16* wk2 = wic + (khw + 2) * 4096;
#pragma unroll
            for (int ks = 0; ks < 4; ++ks) {
                abuf[(khw + 2) % 3][ks * 2]     = *(const bf16x8*)(wk2 + ks * 1024);
                abuf[(khw + 2) % 3][ks * 2 + 1] = *(const bf16x8*)(wk2 + ks * 1024 + 512);
            }
        }
        int kh = khw / 5, kw = khw - kh * 5;
        int doff = (kh * 42 + kw) * 136;
#pragma unroll
        for (int ks = 0; ks < 4; ++ks) {
            bf16x8 a0 = abuf[khw % 3][ks * 2];
            bf16x8 a1 = abuf[khw % 3][ks * 2 + 1];
#pragma unroll
            for (int nt = 0; nt < 2; ++nt) {
                bf16x8 bfr = *(const bf16x8*)((char*)ins + baseN[nt] + doff + ks * 32);
                acc[0][nt] = __builtin_amdgcn_mfma_f32_32x32x16_bf16(a0, bfr, acc[0][nt], 0, 0, 0);
                acc[1][nt] = __builtin_amdgcn_mfma_f32_32x32x16_bf16(a1, bfr, acc[1][nt], 0, 0, 0);
            }
        }
    }
    float* pdst = p01 + (size_t)icc * 5914624;
#pragma unroll
    for (int nt = 0; nt < 2; ++nt) {
        int pi = posi[nt];
        if (pi < validp) {
            int r = pi / 38, c = pi - r * 38;
            int oh = row0 + r;
            size_t obase = (((size_t)b * 38 + oh) * 38 + c) * 64;
#pragma unroll
            for (int mt = 0; mt < 2; ++mt) {
#pragma unroll
                for (int g2 = 0; g2 < 4; ++g2) {
                    int oc0 = mt * 32 + g2 * 8 + h * 4;
                    floatx4 pv;
                    pv[0] = acc[mt][nt][g2 * 4 + 0];
                    pv[1] = acc[mt][nt][g2 * 4 + 1];
                    pv[2] = acc[mt][nt][g2 * 4 + 2];
                    pv[3] = acc[mt][nt][g2 * 4 + 3];
                    *(floatx4*)(pdst + obase + oc0) = pv;
                }
            }
        }
    }
}

// ---- reduce: h2n = bf16(p0 + p1 + b2) -- pure streaming, HBM-rate ---------
__global__ __launch_bounds__(256) void k_reduce_h2(const float* __restrict__ p01,
                                                   const float* __restrict__ b2,
                                                   __bf16* __restrict__ h2n) {
    int i = blockIdx.x * 256 + threadIdx.x;          // 1478656 groups of 4
    if (i >= 1478656) return;
    size_t e = (size_t)i * 4;
    floatx4 a = *(const floatx4*)(p01 + e);
    floatx4 b = *(const floatx4*)(p01 + 5914624 + e);
    floatx4 bv = *(const floatx4*)(b2 + ((i * 4) & 63));
    bf16x4 pk;
    pk.x = (__bf16)(a[0] + b[0] + bv[0]);
    pk.y = (__bf16)(a[1] + b[1] + bv[1]);
    pk.z = (__bf16)(a[2] + b[2] + bv[2]);
    pk.w = (__bf16)(a[3] + b[3] + bv[3]);
    *(bf16x4*)(h2n + e) = pk;
}

// ---- caps conv 8x8 s2 via MFMA 32x32x16, icc-split -> fp32 partials -------
// grid (8, 64, 2); block = ONE icc half (32 ch), one stage phase, writes
// pc[icc][b][1024][32] f32 (no bias, no squash).
__global__ __launch_bounds__(256, 4) void k_convcaps(const __bf16* __restrict__ h2n,
                                                     const __bf16* __restrict__ wca,
                                                     float* __restrict__ pc) {
    __shared__ __bf16 ins[13680];                    // 380 * 72 B = 27360 B
    int g = blockIdx.x, b = blockIdx.y, icc = blockIdx.z;
    int t = threadIdx.x;
    int lane = t & 63, ct = t >> 6;                  // wave = capsule type
    int c32 = lane & 31, h = lane >> 5;
    int rloc = c32 >> 4, cx = c32 & 15;
    int ic0 = icc * 32;

    floatx16 acc;
#pragma unroll
    for (int i = 0; i < 16; ++i) acc[i] = 0.f;

    int Bbase = (76 * rloc + cx) * 72 + h * 16;      // lane byte base in slab
    {
        uint4 rb[6];
        int lo[6];
#pragma unroll
        for (int k = 0; k < 6; ++k) {
            int j = k * 256 + t;
            if (j > 1519) j -= 256;                  // only k=5, t>=240
            int r = j / 152, rem = j - r * 152;
            int c = rem >> 2, s = rem & 3;
            rb[k] = *(const uint4*)(h2n + ((((size_t)b * 38 + 4 * g + r) * 38 + c) * 64 + ic0 + s * 8));
            int X = (r * 2 + (c & 1)) * 19 + (c >> 1);
            lo[k] = X * 72 + s * 16;
        }
#pragma unroll
        for (int k = 0; k < 6; ++k)
            *(uint4*)((char*)ins + lo[k]) = rb[k];
    }
    __syncthreads();
    const __bf16* wic = wca + ((size_t)icc * 64 * 8 + ct) * 512 + (lane << 3);
#pragma unroll
    for (int khw = 0; khw < 64; ++khw) {
        int kh = khw >> 3, kw = khw & 7;
        int par = kw & 1, k2 = kw >> 1;
        int doff = ((kh * 2 + par) * 19 + k2) * 72;
        const __bf16* wk = wic + khw * 4096;         // 2 ks x 4 ct x 512
#pragma unroll
        for (int ks = 0; ks < 2; ++ks) {
            bf16x8 af = *(const bf16x8*)(wk + ks * 2048);
            bf16x8 bfr = *(const bf16x8*)((char*)ins + Bbase + doff + ks * 32);
            acc = __builtin_amdgcn_mfma_f32_32x32x16_bf16(af, bfr, acc, 0, 0, 0);
        }
    }
    int pos = (2 * g + rloc) * 16 + cx;              // y*16 + x
    float* dst = pc + (size_t)icc * 2097152 + (((size_t)b * 1024 + ct * 256 + pos) * 32);
#pragma unroll
    for (int g2 = 0; g2 < 4; ++g2) {
        floatx4 pv;
        pv[0] = acc[g2 * 4 + 0];
        pv[1] = acc[g2 * 4 + 1];
        pv[2] = acc[g2 * 4 + 2];
        pv[3] = acc[g2 * 4 + 3];
        *(floatx4*)(dst + g2 * 8 + h * 4) = pv;
    }
}

// ---- squash: ub = squash(pc0 + pc1 + bc) -- 20MB streaming ----------------
// capsule i = b*1024 + ct*256 + pos; dim d -> channel ct*32+d.
__global__ __launch_bounds__(256) void k_squash(const float* __restrict__ pc,
                                                const float* __restrict__ bc,
                                                __bf16* __restrict__ ub) {
    int i = blockIdx.x * 256 + threadIdx.x;          // 65536 capsules
    if (i >= 65536) return;
    int ct = (i >> 8) & 3;
    const float* p0 = pc + (size_t)i * 32;
    const float* p1 = pc + 2097152 + (size_t)i * 32;
    const float* bv = bc + ct * 32;
    float vals[32];
    float n2 = 0.f;
#pragma unroll
    for (int k = 0; k < 8; ++k) {
        floatx4 a = *(const floatx4*)(p0 + k * 4);
        floatx4 b = *(const floatx4*)(p1 + k * 4);
        floatx4 bb = *(const floatx4*)(bv + k * 4);
#pragma unroll
        for (int e = 0; e < 4; ++e) {
            float v = a[e] + b[e] + bb[e];
            vals[k * 4 + e] = v;
            n2 = fmaf(v, v, n2);
        }
    }
    float scale = (n2 / (1.f + n2)) / sqrtf(n2 + EPSF);
    __bf16* dst = ub + (size_t)i * 32;
#pragma unroll
    for (int k = 0; k < 8; ++k) {
        bf16x4 pk;
        pk.x = (__bf16)(vals[k * 4 + 0] * scale);
        pk.y = (__bf16)(vals[k * 4 + 1] * scale);
        pk.z = (__bf16)(vals[k * 4 + 2] * scale);
        pk.w = (__bf16)(vals[k * 4 + 3] * scale);
        *(bf16x4*)(dst + k * 4) = pk;
    }
}

// ---- u_hat: ub bf16 [64,1024,32] x wrb bf16 [1024,10,16,32] -> uhT bf16 ---
__global__ __launch_bounds__(256, 2) void k_uhat(const __bf16* __restrict__ ub,
                                                 const __bf16* __restrict__ wrb,
                                                 __bf16* __restrict__ uhT) {
    int pt = blockIdx.x, ts = blockIdx.y, bz = blockIdx.z;
    int t = threadIdx.x;
    int p = pt * 64 + (t & 63);
    int q = t >> 6;
    bf16x8 wf[4][4];
#pragma unroll
    for (int o4 = 0; o4 < 4; ++o4)
#pragma unroll
        for (int j = 0; j < 4; ++j)
            wf[o4][j] = *(const bf16x8*)(wrb + (((size_t)p * 10 + ts) * 16 + q * 4 + o4) * 32 + j * 8);
#pragma unroll 1
    for (int bi = 0; bi < 16; ++bi) {
        int b = bz * 16 + bi;
        bf16x8 uf[4];
        const bf16x8* up = (const bf16x8*)(ub + ((size_t)b * 1024 + p) * 32);
#pragma unroll
        for (int j = 0; j < 4; ++j) uf[j] = up[j];
#pragma unroll
        for (int o4 = 0; o4 < 4; ++o4) {
            float s = 0.f;
#pragma unroll
            for (int j = 0; j < 4; ++j)
#pragma unroll
                for (int e = 0; e < 8; ++e)
                    s = fmaf((float)uf[j][e], (float)wf[o4][j][e], s);
            uhT[(((size_t)b * 10 + ts) * 16 + q * 4 + o4) * 1024 + p] = (__bf16)s;
        }
    }
}

// ---- fused routing step with bl ping-pong ---------------------------------
__global__ __launch_bounds__(256) void k_route(const __bf16* __restrict__ uhT,
                                               const float* __restrict__ blR,
                                               float* __restrict__ blW,
                                               float* __restrict__ out,
                                               int first, int dob, int last) {
    __shared__ __bf16 uh_s[16384];                   // 32 KB: [o][p]
    __shared__ float sred[4][16];
    __shared__ float vs[16];
    int b = blockIdx.x, tt = blockIdx.y;
    int t = threadIdx.x;
    const __bf16* uhb = uhT + ((size_t)b * 10 + tt) * 16384;
#pragma unroll
    for (int k = 0; k < 8; ++k) {
        int j = k * 256 + t;
        *(uint4*)((char*)uh_s + j * 16) = *(const uint4*)((const char*)uhb + j * 16);
    }
    __syncthreads();

    // ---- s-phase
    float acc[16];
#pragma unroll
    for (int o = 0; o < 16; ++o) acc[o] = 0.f;
    const float* blb = blR + b * 10240;
    for (int p = t; p < 1024; p += 256) {
        float c;
        if (first) {
            c = 0.1f;
        } else {
            float den = 0.f, et = 0.f;
#pragma unroll
            for (int tp = 0; tp < 10; ++tp) {
                float e = expf(blb[tp * 1024 + p]);
                den += e;
                if (tp == tt) et = e;
            }
            c = et / den;
        }
#pragma unroll
        for (int o = 0; o < 16; ++o)
            acc[o] = fmaf(c, (float)uh_s[o * 1024 + p], acc[o]);
    }
    int lane = t & 63, wid = t >> 6;
#pragma unroll
    for (int o = 0; o < 16; ++o) {
        float v = acc[o];
#pragma unroll
        for (int off = 32; off >= 1; off >>= 1) v += __shfl_xor(v, off, 64);
        if (lane == 0) sred[wid][o] = v;
    }
    __syncthreads();
    if (t < 16) {
        float s = (sred[0][t] + sred[1][t]) + (sred[2][t] + sred[3][t]);
        float n2 = s * s;
#pragma unroll
        for (int off = 1; off < 16; off <<= 1) n2 += __shfl_xor(n2, off, 16);
        float scale = (n2 / (1.f + n2)) / sqrtf(n2 + EPSF);
        vs[t] = s * scale;
        if (last && t == 0) {
            float sv2 = n2 * scale * scale;
            out[b * 10 + tt] = sqrtf(sv2 + EPSF);
        }
    }
    __syncthreads();

    // ---- b-phase: read own slice of blR, write own slice of blW
    if (dob) {
        const float* blr = blR + (b * 10 + tt) * 1024;
        float* blw = blW + (b * 10 + tt) * 1024;
        for (int p = t; p < 1024; p += 256) {
            float d = 0.f;
#pragma unroll
            for (int o = 0; o < 16; ++o) d = fmaf((float)uh_s[o * 1024 + p], vs[o], d);
            blw[p] = first ? d : (blr[p] + d);
        }
    }
}

// ---------------------------------------------------------------------------
extern "C" void kernel_launch(void* const* d_in, const int* in_sizes, int n_in,
                              void* d_out, int out_size, void* d_ws, size_t ws_size,
                              hipStream_t stream) {
    const float* x  = (const float*)d_in[0];
    const float* w1 = (const float*)d_in[1];
    const float* b1 = (const float*)d_in[2];
    const float* w2 = (const float*)d_in[3];
    const float* b2 = (const float*)d_in[4];
    const float* wc = (const float*)d_in[5];
    const float* bc = (const float*)d_in[6];
    const float* Wr = (const float*)d_in[7];
    float* out = (float*)d_out;
    float* ws  = (float*)d_ws;

    // workspace layout (float offsets)
    __bf16* w2a = (__bf16*)(ws);                  // 204800 bf16
    __bf16* wca = (__bf16*)(ws + 102400);         // 524288 bf16
    __bf16* w1b = (__bf16*)(ws + 364544);         // 12288 bf16
    __bf16* h1n = (__bf16*)(ws + 375040);         // 14450688 bf16
    __bf16* h2n = (__bf16*)(ws + 7600384);        // 5914624 bf16
    __bf16* ub  = (__bf16*)(ws + 12654848);       // 2097152 bf16
    float*  blA = ws + 14752000;                  // 655360 f
    __bf16* wrb = (__bf16*)(ws + 15417600);       // 5242880 bf16
    float*  p01 = ws + 18039040;                  // 2 x 5914624 f32 partials
    float*  pc  = ws + 18039040;                  // overlays p01 (dead after reduce)
    float*  blB = ws + 29868288;                  // 655360 f (ping-pong)
    __bf16* uhT = (__bf16*)(ws + 375040);         // overlays h1n (dead by k_uhat)

    k_t_all<<<23376, 256, 0, stream>>>(Wr, wc, w2, w1, wrb, wca, w2a, w1b);
    k_conv1_mfma<<<dim3(42, 2, 64), 256, 0, stream>>>(x, w1b, b1, h1n);
    k_conv2<<<dim3(8, 64, 2), 256, 0, stream>>>(h1n, w2a, p01);
    k_reduce_h2<<<5776, 256, 0, stream>>>(p01, b2, h2n);
    k_convcaps<<<dim3(8, 64, 2), 256, 0, stream>>>(h2n, wca, pc);
    k_squash<<<256, 256, 0, stream>>>(pc, bc, ub);
    k_uhat<<<dim3(16, 10, 4), 256, 0, stream>>>(ub, wrb, uhT);
    k_route<<<dim3(64, 10), 256, 0, stream>>>(uhT, blA, blA, out, 1, 1, 0);
    k_route<<<dim3(64, 10), 256, 0, stream>>>(uhT, blA, blB, out, 0, 1, 0);
    k_route<<<dim3(64, 10), 256, 0, stream>>>(uhT, blB, blB, out, 0, 0, 1);
}